// Round 16
// baseline (868.007 us; speedup 1.0000x reference)
//
#include <hip/hip_runtime.h>
#include <hip/hip_fp16.h>

#define P_ 3
#define N_ 100000
#define M_ 30000
#define E_ 200000
#define C_ 5
#define FP_ 64
#define FN_ 32
#define PFP_ 192     // P*FP
#define FPFN_ 96     // FP+FN
#define PE_ 600000   // P*E
#define PN_ 300000   // P*N
#define PM_ 90000    // P*M
#define NT_ 32       // nodes per projx tile
#define XSP_ 324     // padded xs row stride in halves (162 words == 2 mod 32)
#define TILES_ ((N_ + NT_ - 1) / NT_)     // 3125
#define NTD_ 64      // nodes per decoder tile
#define TILESD_ ((N_ + NTD_ - 1) / NTD_)  // 1563
#define CFN_ 160     // C*FN
#define NW1_ 92160   // 15*64*96
#define NW2_ 61440   // 15*64*64
#define NB_S_ ((PN_ + 1023) / 1024)       // 293
#define NB_D_ ((PM_ + 1023) / 1024)       // 88
#define NB_CNT_ ((PE_ + 255) / 256)       // 2344 count blocks
#define NB_WC_ ((NW1_ + 255) / 256)       // 360 wconv blocks
#define NB_PROJ_ (P_ * TILES_)            // 9375
#define NB_FILL_ ((PE_ + 319) / 320)      // 1875

typedef _Float16 f16x8 __attribute__((ext_vector_type(8)));
typedef float f32x4 __attribute__((ext_vector_type(4)));

__device__ __forceinline__ float fast_tanh(float v) {
  float x = fminf(fmaxf(v, -15.0f), 15.0f);
  float t = __expf(2.0f * x);
  return __fdividef(t - 1.0f, t + 1.0f);
}

__device__ __forceinline__ f16x8 ld8(const __half* p) {
  return *(const f16x8*)(const void*)p;
}

// ====================== count + wconv (fused) ======================
__global__ void k_countw(const int* __restrict__ esrc, const int* __restrict__ edst,
                         int* __restrict__ cnt_src, int* __restrict__ cnt_dst,
                         const float* __restrict__ Wd1, const float* __restrict__ Wd2,
                         __half* __restrict__ w1h, __half* __restrict__ w2h) {
  int b = blockIdx.x;
  if (b < NB_CNT_) {
    int i = b * 256 + threadIdx.x;
    if (i >= PE_) return;
    int p = i / E_;
    atomicAdd(&cnt_src[p * N_ + esrc[i]], 1);
    atomicAdd(&cnt_dst[p * M_ + edst[i]], 1);
  } else {
    int i = (b - NB_CNT_) * 256 + threadIdx.x;
    if (i < NW1_) w1h[i] = __float2half(Wd1[i]);
    if (i < NW2_) w2h[i] = __float2half(Wd2[i]);
  }
}

__global__ void k_scan1c(const int* __restrict__ in_s, int* __restrict__ out_s,
                         int* __restrict__ aux_s,
                         const int* __restrict__ in_d, int* __restrict__ out_d,
                         int* __restrict__ aux_d) {
  __shared__ int lds[256];
  int b = blockIdx.x, t = threadIdx.x;
  const int* in;
  int* out;
  int* aux;
  int n;
  if (b < NB_S_) { in = in_s; out = out_s; aux = aux_s; n = PN_; }
  else           { b -= NB_S_; in = in_d; out = out_d; aux = aux_d; n = PM_; }
  int base = b * 1024 + t * 4;
  int v0 = (base + 0 < n) ? in[base + 0] : 0;
  int v1 = (base + 1 < n) ? in[base + 1] : 0;
  int v2 = (base + 2 < n) ? in[base + 2] : 0;
  int v3 = (base + 3 < n) ? in[base + 3] : 0;
  lds[t] = v0 + v1 + v2 + v3;
  __syncthreads();
  for (int off = 1; off < 256; off <<= 1) {
    int xv = (t >= off) ? lds[t - off] : 0;
    __syncthreads();
    lds[t] += xv;
    __syncthreads();
  }
  if (t == 255) aux[b] = lds[255];
  int run = (t == 0) ? 0 : lds[t - 1];
  if (base + 0 < n) out[base + 0] = run; run += v0;
  if (base + 1 < n) out[base + 1] = run; run += v1;
  if (base + 2 < n) out[base + 2] = run; run += v2;
  if (base + 3 < n) out[base + 3] = run;
}

__global__ void k_scan2c(int* __restrict__ aux_s, int* __restrict__ end_s,
                         int* __restrict__ aux_d, int* __restrict__ end_d) {
  __shared__ int lds[1024];
  int t = threadIdx.x;
  int* aux = (blockIdx.x == 0) ? aux_s : aux_d;
  int* offe = (blockIdx.x == 0) ? end_s : end_d;
  int nb = (blockIdx.x == 0) ? NB_S_ : NB_D_;
  lds[t] = (t < nb) ? aux[t] : 0;
  __syncthreads();
  for (int off = 1; off < 1024; off <<= 1) {
    int xv = (t >= off) ? lds[t - off] : 0;
    __syncthreads();
    lds[t] += xv;
    __syncthreads();
  }
  if (t < nb) aux[t] = (t == 0) ? 0 : lds[t - 1];
  if (t == 0) offe[0] = lds[nb - 1];
}

__global__ void k_scan3c(int* __restrict__ off_s, const int* __restrict__ aux_s,
                         int* __restrict__ cur_s,
                         int* __restrict__ off_d, const int* __restrict__ aux_d,
                         int* __restrict__ cur_d) {
  int i = blockIdx.x * 256 + threadIdx.x;
  if (i < PN_) {
    int v = off_s[i] + aux_s[i >> 10];
    off_s[i] = v;
    cur_s[i] = v;
  } else if (i < PN_ + PM_) {
    int j = i - PN_;
    int v = off_d[j] + aux_d[j >> 10];
    off_d[j] = v;
    cur_d[j] = v;
  }
}

// ====================== projx (+ xdot, + xh fused in stage) + fill =============
// blocks [0, NB_PROJ_): projx; beyond: CSR fill (lists store node AND edge id)
__global__ __launch_bounds__(320) void k_projfill(
    const float* __restrict__ x, const float* __restrict__ Wn1,
    const float* __restrict__ We,
    __half* __restrict__ y, float* __restrict__ xdot,
    __half* __restrict__ xh, int write_xh,
    const int* __restrict__ esrc, const int* __restrict__ edst,
    int* __restrict__ cur_src, int* __restrict__ cur_dst,
    int* __restrict__ list_src, int* __restrict__ list_src_e,
    int* __restrict__ list_dst, int* __restrict__ list_dst_e) {
  __shared__ __align__(16) __half xs[NT_ * XSP_];   // 20.3 KB (padded rows)
  int bp = blockIdx.x;
  int t = threadIdx.x;

  if (bp >= NB_PROJ_) {                 // ---- fill role ----
    int i = (bp - NB_PROJ_) * 320 + t;
    if (i < PE_) {
      int p = i / E_;
      int s = esrc[i], d = edst[i];
      int ps = atomicAdd(&cur_src[p * N_ + s], 1);
      list_src[ps] = d;
      list_src_e[ps] = i;
      int pd = atomicAdd(&cur_dst[p * M_ + d], 1);
      list_dst[pd] = s;
      list_dst_e[pd] = i;
    }
    return;
  }

  int p = bp / TILES_, tile = bp % TILES_;
  int base = tile * NT_;
  int rows = min(NT_, N_ - base);
  int g = t / CFN_, u = t % CFN_;
  int c = u >> 5;

  __half2 w[32];
  {
    const float* wr = &Wn1[(size_t)u * PFP_ + p * FP_];
    #pragma unroll
    for (int i = 0; i < 32; ++i) w[i] = __floats2half2_rn(wr[2*i], wr[2*i+1]);
  }

  // ---- stage x -> xs (padded) AND xh (dense) in one pass ----
  const float* xb = x + (size_t)(p * N_ + base) * 320;
  __half* xo = xh + (size_t)(p * N_ + base) * 320;
  int chunks = rows * 40;              // 8-half chunks per row
  for (int idx = t; idx < chunks; idx += 320) {
    int row = idx / 40, col = idx % 40;
    const float4* s4 = (const float4*)&xb[row * 320 + col * 8];
    float4 v0 = s4[0], v1 = s4[1];
    union { __half2 h[4]; float4 f; } u4;
    u4.h[0] = __floats2half2_rn(v0.x, v0.y);
    u4.h[1] = __floats2half2_rn(v0.z, v0.w);
    u4.h[2] = __floats2half2_rn(v1.x, v1.y);
    u4.h[3] = __floats2half2_rn(v1.z, v1.w);
    __half2* d = (__half2*)&xs[row * XSP_ + col * 8];
    d[0] = u4.h[0]; d[1] = u4.h[1]; d[2] = u4.h[2]; d[3] = u4.h[3];
    if (write_xh) *(float4*)&xo[row * 320 + col * 8] = u4.f;
  }
  __syncthreads();

  for (int r = g; r < rows; r += 2) {
    const __half2* xr = (const __half2*)&xs[r * XSP_ + c * FP_];
    __half2 acc = __floats2half2_rn(0.f, 0.f);
    #pragma unroll
    for (int i = 0; i < 32; ++i) acc = __hfma2(xr[i], w[i], acc);
    float s = __low2float(acc) + __high2float(acc);
    y[(size_t)(p * N_ + base + r) * CFN_ + u] = __float2half(s);
  }

  // fused xdot: t -> (cx = t>>6, node = t&63); only node < rows active
  {
    int cx = t >> 6, nodex = t & 63;
    if (nodex < rows) {
      const __half2* xr = (const __half2*)&xs[nodex * XSP_ + cx * FP_];
      const float2* wer = (const float2*)&We[(p * C_ + cx) * FPFN_];
      float s = 0.f;
      #pragma unroll
      for (int i = 0; i < 32; ++i) {
        float2 wv = wer[i];
        __half2 xv = xr[i];
        s += __low2float(xv) * wv.x + __high2float(xv) * wv.y;
      }
      xdot[(size_t)(p * N_ + base + nodex) * C_ + cx] = s;
    }
  }
}

// ====================== nexus: gather y; MLP; + fused edge-weight softmax ======
__global__ __launch_bounds__(320) void k_nexus(
    const __half* __restrict__ y,
    const int* __restrict__ off_dst, const int* __restrict__ list_dst,
    const int* __restrict__ list_dst_e, const int* __restrict__ esrc,
    const float* __restrict__ bn1,
    const float* __restrict__ Wn2, const float* __restrict__ bn2,
    const float* __restrict__ We,
    const float* __restrict__ xdot, const float* __restrict__ be,
    __half* __restrict__ nout, __half* __restrict__ wbuf) {
  __shared__ float part[4][CFN_];
  __shared__ __align__(16) float h1S[CFN_];
  __shared__ __align__(16) float h2S[CFN_];
  __shared__ float ndS[P_ * C_];
  __shared__ float beS[P_ * C_];
  int m = blockIdx.x;
  int t = threadIdx.x;               // 320 = 4 groups x 80 half2-lanes
  int g = t / 80, u2 = t % 80;

  float afx = 0.f, afy = 0.f;
  #pragma unroll
  for (int p = 0; p < P_; ++p) {
    int o0 = off_dst[p * M_ + m];
    int o1 = off_dst[p * M_ + m + 1];
    const __half2* yp2 = (const __half2*)(y + (size_t)p * N_ * CFN_);
    for (int e0 = o0 + g; e0 < o1; e0 += 8) {   // batch-2 per group
      int e1 = e0 + 4;
      int s0 = list_dst[e0];
      int s1 = list_dst[e1 < o1 ? e1 : e0];
      __half2 v0 = yp2[(size_t)s0 * 80 + u2];
      __half2 v1 = yp2[(size_t)s1 * 80 + u2];
      afx += __low2float(v0); afy += __high2float(v0);
      if (e1 < o1) { afx += __low2float(v1); afy += __high2float(v1); }
    }
  }
  part[g][2 * u2]     = afx;
  part[g][2 * u2 + 1] = afy;
  __syncthreads();
  if (t < CFN_) {
    float pre = part[0][t] + part[1][t] + part[2][t] + part[3][t] + bn1[t];
    h1S[t] = fast_tanh(pre);
  }
  __syncthreads();
  if (t < CFN_) {
    int c = t >> 5;
    const float4* f4 = (const float4*)&h1S[c * FN_];
    const float4* w4 = (const float4*)&Wn2[(size_t)t * FN_];
    float a = bn2[t];
    #pragma unroll
    for (int i = 0; i < FN_ / 4; ++i) {
      float4 f = f4[i], wv = w4[i];
      a += f.x * wv.x + f.y * wv.y + f.z * wv.z + f.w * wv.w;
    }
    float nv = fast_tanh(a);
    h2S[t] = nv;
    nout[(size_t)m * CFN_ + t] = __float2half(nv);
  }
  __syncthreads();
  if (t < P_ * C_) {                 // ndot kept in LDS only
    int p = t / C_, cc = t % C_;
    const float* wv = &We[(p * C_ + cc) * FPFN_ + FP_];
    float a = 0.f;
    #pragma unroll
    for (int j = 0; j < FN_; ++j) a += h2S[cc * FN_ + j] * wv[j];
    ndS[t] = a;
    beS[t] = be[t];
  }
  __syncthreads();
  // ---- edge-weight phase: softmax once per edge, wbuf[i][c] fp16 ----
  #pragma unroll
  for (int p = 0; p < P_; ++p) {
    int o0 = off_dst[p * M_ + m];
    int o1 = off_dst[p * M_ + m + 1];
    for (int e = o0 + t; e < o1; e += 320) {
      int i = list_dst_e[e];
      int src = esrc[i];
      const float* xd = &xdot[(size_t)(p * N_ + src) * C_];
      float lg[C_];
      #pragma unroll
      for (int cc = 0; cc < C_; ++cc) lg[cc] = xd[cc] + ndS[p * C_ + cc] + beS[p * C_ + cc];
      float mx = fmaxf(fmaxf(fmaxf(lg[0], lg[1]), fmaxf(lg[2], lg[3])), lg[4]);
      float s = 0.f;
      #pragma unroll
      for (int cc = 0; cc < C_; ++cc) { lg[cc] = __expf(lg[cc] - mx); s += lg[cc]; }
      float inv = __fdividef(1.0f, s);
      __half* wp = &wbuf[(size_t)i * C_];
      #pragma unroll
      for (int cc = 0; cc < C_; ++cc) wp[cc] = __float2half(lg[cc] * inv);
    }
  }
}

// ====================== MFMA decoder: precomputed weights, unroll-2 gather =====
// Fragments: A row=l&15, k=8*(l>>4)+j; B col=l&15, k=8*(l>>4)+j;
//            D col=l&15, row=4*(l>>4)+reg.
template<int XH>
__global__ __launch_bounds__(128, 6) void k_dec(
    const float* __restrict__ x, const __half* __restrict__ xh,
    const __half* __restrict__ nout, const __half* __restrict__ wbuf,
    const int* __restrict__ off_src, const int* __restrict__ list_src,
    const int* __restrict__ list_src_e,
    const __half* __restrict__ w1h, const float* __restrict__ bd1,
    const __half* __restrict__ w2h, const float* __restrict__ bd2,
    float* __restrict__ out) {
  __shared__ __align__(16) __half featS[NTD_ * 104];   // 13.3 KB

  int bp = blockIdx.x;
  int pc = bp / TILESD_;
  int tile = bp % TILESD_;
  int p = pc / C_, c = pc % C_;
  int base = tile * NTD_;
  int rows = min(NTD_, N_ - base);

  int t = threadIdx.x;
  int w = t >> 6, l = t & 63;
  int l15 = l & 15, l4 = l >> 4;

  // ---- stage x ----
  if constexpr (XH) {
    for (int idx = t; idx < NTD_ * 8; idx += 128) {
      int node = idx >> 3, q = idx & 7;
      if (node < rows) {
        float4 v = *(const float4*)&xh[(size_t)(p * N_ + base + node) * 320 + c * 64 + q * 8];
        *(float4*)&featS[node * 104 + q * 8] = v;
      }
    }
  } else {
    for (int idx = t; idx < NTD_ * 16; idx += 128) {
      int node = idx >> 4, fq = idx & 15;
      if (node < rows) {
        float4 v = *(const float4*)&x[(size_t)(p * N_ + base + node) * 320 + c * 64 + fq * 4];
        __half2* dst = (__half2*)&featS[node * 104 + fq * 4];
        dst[0] = __floats2half2_rn(v.x, v.y);
        dst[1] = __floats2half2_rn(v.z, v.w);
      }
    }
  }
  // ---- fused aggregation: precomputed weights, 2 threads/node, unroll-2 edges -
  {
    int nd = t >> 1, hf = t & 1;
    if (nd < rows) {
      int pn = p * N_ + base + nd;
      int o0 = off_src[pn], o1 = off_src[pn + 1];
      float acc[16];
      #pragma unroll
      for (int i = 0; i < 16; ++i) acc[i] = 0.f;
      for (int e = o0; e < o1; e += 2) {
        int e1 = e + 1;
        bool has1 = (e1 < o1);
        int d0 = list_src[e];
        int i0 = list_src_e[e];
        int d1 = list_src[has1 ? e1 : e];
        int i1 = list_src_e[has1 ? e1 : e];
        float wg0 = __half2float(wbuf[(size_t)i0 * C_ + c]);
        float wg1 = __half2float(wbuf[(size_t)i1 * C_ + c]);
        const __half2* nr0 = (const __half2*)&nout[(size_t)d0 * CFN_ + c * FN_ + hf * 16];
        const __half2* nr1 = (const __half2*)&nout[(size_t)d1 * CFN_ + c * FN_ + hf * 16];
        __half2 v0[8], v1[8];
        #pragma unroll
        for (int i = 0; i < 8; ++i) v0[i] = nr0[i];
        #pragma unroll
        for (int i = 0; i < 8; ++i) v1[i] = nr1[i];
        #pragma unroll
        for (int i = 0; i < 8; ++i) {
          acc[2 * i]     += wg0 * __low2float(v0[i]);
          acc[2 * i + 1] += wg0 * __high2float(v0[i]);
        }
        if (has1) {
          #pragma unroll
          for (int i = 0; i < 8; ++i) {
            acc[2 * i]     += wg1 * __low2float(v1[i]);
            acc[2 * i + 1] += wg1 * __high2float(v1[i]);
          }
        }
      }
      float invd = __fdividef(1.0f, fmaxf((float)(o1 - o0), 1.0f));
      __half2* dst2 = (__half2*)&featS[nd * 104 + 64 + hf * 16];
      #pragma unroll
      for (int i = 0; i < 8; ++i)
        dst2[i] = __floats2half2_rn(acc[2 * i] * invd, acc[2 * i + 1] * invd);
    }
  }
  __syncthreads();

  int rbase = w * 32;   // this wave's node window [rbase, rbase+32)
  const __half* w1g = w1h + (size_t)(p * C_ + c) * 64 * 96;
  const __half* w2g = w2h + (size_t)(p * C_ + c) * 64 * 64;

  // ---- L1: acc[rt][tt] += A(feat) x B(W1) ----
  f32x4 acc[2][4];
  #pragma unroll
  for (int tt = 0; tt < 4; ++tt) {
    float bv = bd1[(p * C_ + c) * FP_ + tt * 16 + l15];
    #pragma unroll
    for (int rt = 0; rt < 2; ++rt) acc[rt][tt] = (f32x4){bv, bv, bv, bv};
  }
  #pragma unroll
  for (int s = 0; s < 3; ++s) {
    f16x8 a0 = ld8(&featS[(rbase + l15) * 104 + s * 32 + l4 * 8]);
    f16x8 a1 = ld8(&featS[(rbase + 16 + l15) * 104 + s * 32 + l4 * 8]);
    #pragma unroll
    for (int tt = 0; tt < 4; ++tt) {
      f16x8 b = ld8(&w1g[(tt * 16 + l15) * 96 + s * 32 + l4 * 8]);
      acc[0][tt] = __builtin_amdgcn_mfma_f32_16x16x32_f16(a0, b, acc[0][tt], 0, 0, 0);
      acc[1][tt] = __builtin_amdgcn_mfma_f32_16x16x32_f16(a1, b, acc[1][tt], 0, 0, 0);
    }
  }
  // tanh -> h overlaid into featS cols 0..63 (same-wave rows only)
  #pragma unroll
  for (int rt = 0; rt < 2; ++rt)
    #pragma unroll
    for (int tt = 0; tt < 4; ++tt) {
      #pragma unroll
      for (int r = 0; r < 4; ++r) {
        int nrow = rbase + rt * 16 + l4 * 4 + r;
        featS[nrow * 104 + tt * 16 + l15] = __float2half(fast_tanh(acc[rt][tt][r]));
      }
    }

  // ---- L2: acc2 += A(h in featS) x B(W2) ----
  f32x4 acc2[2][4];
  #pragma unroll
  for (int tt = 0; tt < 4; ++tt) {
    float bv = bd2[(p * C_ + c) * FP_ + tt * 16 + l15];
    #pragma unroll
    for (int rt = 0; rt < 2; ++rt) acc2[rt][tt] = (f32x4){bv, bv, bv, bv};
  }
  #pragma unroll
  for (int s = 0; s < 2; ++s) {
    f16x8 a0 = ld8(&featS[(rbase + l15) * 104 + s * 32 + l4 * 8]);
    f16x8 a1 = ld8(&featS[(rbase + 16 + l15) * 104 + s * 32 + l4 * 8]);
    #pragma unroll
    for (int tt = 0; tt < 4; ++tt) {
      f16x8 b = ld8(&w2g[(tt * 16 + l15) * 64 + s * 32 + l4 * 8]);
      acc2[0][tt] = __builtin_amdgcn_mfma_f32_16x16x32_f16(a0, b, acc2[0][tt], 0, 0, 0);
      acc2[1][tt] = __builtin_amdgcn_mfma_f32_16x16x32_f16(a1, b, acc2[1][tt], 0, 0, 0);
    }
  }
  // tanh -> global
  #pragma unroll
  for (int rt = 0; rt < 2; ++rt)
    #pragma unroll
    for (int tt = 0; tt < 4; ++tt) {
      #pragma unroll
      for (int r = 0; r < 4; ++r) {
        int nrow = rbase + rt * 16 + l4 * 4 + r;
        int node = base + nrow;
        if (node < N_) {
          out[(size_t)(p * N_ + node) * 320 + c * 64 + tt * 16 + l15] =
              fast_tanh(acc2[rt][tt][r]);
        }
      }
    }
}

// ====================== launch ======================
// workspace layout (4-byte words):
#define WS_Y      0ll          // half[48,000,000] = 24,000,000 words
#define WS_NOUT   24000000ll   // half[4,800,000] = 2,400,000 words
#define WS_LISTSE 26400000ll   // int[600,000]
#define WS_WBUF   27000000ll   // half[3,000,000] = 1,500,000 words
#define WS_XDOT   28800000ll   // float[1,500,000]
#define WS_OFFS   30750000ll   // int[300,001]
#define WS_OFFD   31050001ll   // int[90,001]
#define WS_CURS   31140002ll   // int[300,000]
#define WS_CURD   31440002ll   // int[90,000]  (contiguous with CURS)
#define WS_LISTS  31530002ll   // int[600,000]
#define WS_LISTD  32130002ll   // int[600,000]
#define WS_AUX1   32730002ll   // int[512]
#define WS_AUX2   32730514ll   // int[512]
#define WS_W1H    32731026ll   // half[92,160] = 46,080 words
#define WS_W2H    32777106ll   // half[61,440] = 30,720 words
#define WS_LISTDE 32808000ll   // int[600,000]
#define WS_XH     33408000ll   // half[96,000,000] = 48,000,000 words (optional)
#define WS_XH_END_BYTES ((WS_XH + 48000000ll) * 4ll)   // 325,632,000

extern "C" void kernel_launch(void* const* d_in, const int* in_sizes, int n_in,
                              void* d_out, int out_size, void* d_ws, size_t ws_size,
                              hipStream_t stream) {
  const float* x   = (const float*)d_in[0];
  const int* esrc  = (const int*)d_in[2];
  const int* edst  = (const int*)d_in[3];
  const float* Wn1 = (const float*)d_in[4];
  const float* bn1 = (const float*)d_in[5];
  const float* Wn2 = (const float*)d_in[6];
  const float* bn2 = (const float*)d_in[7];
  const float* We  = (const float*)d_in[8];
  const float* be  = (const float*)d_in[9];
  const float* Wd1 = (const float*)d_in[10];
  const float* bd1 = (const float*)d_in[11];
  const float* Wd2 = (const float*)d_in[12];
  const float* bd2 = (const float*)d_in[13];
  float* out = (float*)d_out;

  float* wsf = (float*)d_ws;
  int*   wsi = (int*)d_ws;
  __half* ybuf = (__half*)d_ws;
  __half* nout = (__half*)(wsi + WS_NOUT);
  __half* wbuf = (__half*)(wsi + WS_WBUF);
  float* xdot = wsf + WS_XDOT;
  int* off_src = wsi + WS_OFFS;
  int* off_dst = wsi + WS_OFFD;
  int* cur_src = wsi + WS_CURS;
  int* cur_dst = wsi + WS_CURD;
  int* list_src = wsi + WS_LISTS;
  int* list_src_e = wsi + WS_LISTSE;
  int* list_dst = wsi + WS_LISTD;
  int* list_dst_e = wsi + WS_LISTDE;
  int* aux1 = wsi + WS_AUX1;
  int* aux2 = wsi + WS_AUX2;
  __half* w1h = (__half*)(wsi + WS_W1H);
  __half* w2h = (__half*)(wsi + WS_W2H);
  __half* xh  = (__half*)(wsi + WS_XH);

  int use_xh = (ws_size >= (size_t)WS_XH_END_BYTES) ? 1 : 0;

  // ---- CSR build (consolidated; wconv rides along with count) ----
  hipMemsetAsync(cur_src, 0, (PN_ + PM_) * sizeof(int), stream);
  k_countw<<<NB_CNT_ + NB_WC_, 256, 0, stream>>>(esrc, edst, cur_src, cur_dst,
                                                 Wd1, Wd2, w1h, w2h);
  k_scan1c<<<NB_S_ + NB_D_, 256, 0, stream>>>(cur_src, off_src, aux1,
                                              cur_dst, off_dst, aux2);
  k_scan2c<<<2, 1024, 0, stream>>>(aux1, off_src + PN_, aux2, off_dst + PM_);
  k_scan3c<<<(PN_ + PM_ + 255) / 256, 256, 0, stream>>>(off_src, aux1, cur_src,
                                                        off_dst, aux2, cur_dst);

  // ---- projx + fill (fused, independent work) ----
  k_projfill<<<NB_PROJ_ + NB_FILL_, 320, 0, stream>>>(
      x, Wn1, We, ybuf, xdot, xh, use_xh,
      esrc, edst, cur_src, cur_dst,
      list_src, list_src_e, list_dst, list_dst_e);

  // ---- nexus (+ edge-weight softmax) ----
  k_nexus<<<M_, 320, 0, stream>>>(ybuf, off_dst, list_dst, list_dst_e, esrc,
                                  bn1, Wn2, bn2, We, xdot, be, nout, wbuf);

  // ---- decoder ----
  if (use_xh) {
    k_dec<1><<<P_ * C_ * TILESD_, 128, 0, stream>>>(x, xh, nout, wbuf,
                                                    off_src, list_src, list_src_e,
                                                    w1h, bd1, w2h, bd2, out);
  } else {
    k_dec<0><<<P_ * C_ * TILESD_, 128, 0, stream>>>(x, xh, nout, wbuf,
                                                    off_src, list_src, list_src_e,
                                                    w1h, bd1, w2h, bd2, out);
  }
}

// Round 17
// 795.463 us; speedup vs baseline: 1.0912x; 1.0912x over previous
//
#include <hip/hip_runtime.h>
#include <hip/hip_fp16.h>

#define P_ 3
#define N_ 100000
#define M_ 30000
#define E_ 200000
#define C_ 5
#define FP_ 64
#define FN_ 32
#define PFP_ 192     // P*FP
#define FPFN_ 96     // FP+FN
#define PE_ 600000   // P*E
#define PN_ 300000   // P*N
#define PM_ 90000    // P*M
#define NT_ 64       // nodes per projx tile
#define TILES_ ((N_ + NT_ - 1) / NT_)     // 1563
#define NTD_ 64      // nodes per decoder tile
#define TILESD_ ((N_ + NTD_ - 1) / NTD_)  // 1563
#define CFN_ 160     // C*FN
#define NW1_ 92160   // 15*64*96
#define NW2_ 61440   // 15*64*64
#define NWN1_ 30720  // 160*192
#define NB_S_ ((PN_ + 1023) / 1024)       // 293
#define NB_D_ ((PM_ + 1023) / 1024)       // 88
#define NB_CNT_ ((PE_ + 255) / 256)       // 2344 count blocks
#define NB_WC_ ((NW1_ + 255) / 256)       // 360 wconv blocks
#define NB_PROJ_ (P_ * TILES_)            // 4689
#define NB_FILL_ ((PE_ + 255) / 256)      // 2344

typedef _Float16 f16x8 __attribute__((ext_vector_type(8)));
typedef float f32x4 __attribute__((ext_vector_type(4)));

__device__ __forceinline__ float fast_tanh(float v) {
  float x = fminf(fmaxf(v, -15.0f), 15.0f);
  float t = __expf(2.0f * x);
  return __fdividef(t - 1.0f, t + 1.0f);
}

__device__ __forceinline__ f16x8 ld8(const __half* p) {
  return *(const f16x8*)(const void*)p;
}

// ====================== count + weight conversions (fused) ======================
__global__ void k_countw(const int* __restrict__ esrc, const int* __restrict__ edst,
                         int* __restrict__ cnt_src, int* __restrict__ cnt_dst,
                         const float* __restrict__ Wd1, const float* __restrict__ Wd2,
                         const float* __restrict__ Wn1,
                         __half* __restrict__ w1h, __half* __restrict__ w2h,
                         __half* __restrict__ wn1h) {
  int b = blockIdx.x;
  if (b < NB_CNT_) {
    int i = b * 256 + threadIdx.x;
    if (i >= PE_) return;
    int p = i / E_;
    atomicAdd(&cnt_src[p * N_ + esrc[i]], 1);
    atomicAdd(&cnt_dst[p * M_ + edst[i]], 1);
  } else {
    int i = (b - NB_CNT_) * 256 + threadIdx.x;
    if (i < NW1_) w1h[i] = __float2half(Wd1[i]);
    if (i < NW2_) w2h[i] = __float2half(Wd2[i]);
    if (i < NWN1_) wn1h[i] = __float2half(Wn1[i]);
  }
}

__global__ void k_scan1c(const int* __restrict__ in_s, int* __restrict__ out_s,
                         int* __restrict__ aux_s,
                         const int* __restrict__ in_d, int* __restrict__ out_d,
                         int* __restrict__ aux_d) {
  __shared__ int lds[256];
  int b = blockIdx.x, t = threadIdx.x;
  const int* in;
  int* out;
  int* aux;
  int n;
  if (b < NB_S_) { in = in_s; out = out_s; aux = aux_s; n = PN_; }
  else           { b -= NB_S_; in = in_d; out = out_d; aux = aux_d; n = PM_; }
  int base = b * 1024 + t * 4;
  int v0 = (base + 0 < n) ? in[base + 0] : 0;
  int v1 = (base + 1 < n) ? in[base + 1] : 0;
  int v2 = (base + 2 < n) ? in[base + 2] : 0;
  int v3 = (base + 3 < n) ? in[base + 3] : 0;
  lds[t] = v0 + v1 + v2 + v3;
  __syncthreads();
  for (int off = 1; off < 256; off <<= 1) {
    int xv = (t >= off) ? lds[t - off] : 0;
    __syncthreads();
    lds[t] += xv;
    __syncthreads();
  }
  if (t == 255) aux[b] = lds[255];
  int run = (t == 0) ? 0 : lds[t - 1];
  if (base + 0 < n) out[base + 0] = run; run += v0;
  if (base + 1 < n) out[base + 1] = run; run += v1;
  if (base + 2 < n) out[base + 2] = run; run += v2;
  if (base + 3 < n) out[base + 3] = run;
}

__global__ void k_scan2c(int* __restrict__ aux_s, int* __restrict__ end_s,
                         int* __restrict__ aux_d, int* __restrict__ end_d) {
  __shared__ int lds[1024];
  int t = threadIdx.x;
  int* aux = (blockIdx.x == 0) ? aux_s : aux_d;
  int* offe = (blockIdx.x == 0) ? end_s : end_d;
  int nb = (blockIdx.x == 0) ? NB_S_ : NB_D_;
  lds[t] = (t < nb) ? aux[t] : 0;
  __syncthreads();
  for (int off = 1; off < 1024; off <<= 1) {
    int xv = (t >= off) ? lds[t - off] : 0;
    __syncthreads();
    lds[t] += xv;
    __syncthreads();
  }
  if (t < nb) aux[t] = (t == 0) ? 0 : lds[t - 1];
  if (t == 0) offe[0] = lds[nb - 1];
}

__global__ void k_scan3c(int* __restrict__ off_s, const int* __restrict__ aux_s,
                         int* __restrict__ cur_s,
                         int* __restrict__ off_d, const int* __restrict__ aux_d,
                         int* __restrict__ cur_d) {
  int i = blockIdx.x * 256 + threadIdx.x;
  if (i < PN_) {
    int v = off_s[i] + aux_s[i >> 10];
    off_s[i] = v;
    cur_s[i] = v;
  } else if (i < PN_ + PM_) {
    int j = i - PN_;
    int v = off_d[j] + aux_d[j >> 10];
    off_d[j] = v;
    cur_d[j] = v;
  }
}

// ====================== projx: MFMA y-projection (+ xdot, + xh) + fill =========
// xs rows XOR-swizzled: element h of row r lives at half-offset h ^ ((r&7)<<3).
// y MFMA per c: Y_c[64x32] = X_c[64x64] . W_c^T, B-frags direct from wn1h (L2).
// Fragments: A row=l&15, k=8*(l>>4)+j; B col=l&15, k=8*(l>>4)+j;
//            D col=l&15, row=4*(l>>4)+reg.
__global__ __launch_bounds__(256) void k_projfill(
    const float* __restrict__ x, const __half* __restrict__ wn1h,
    const float* __restrict__ We,
    __half* __restrict__ y, float* __restrict__ xdot,
    __half* __restrict__ xh, int write_xh,
    const int* __restrict__ esrc, const int* __restrict__ edst,
    int* __restrict__ cur_src, int* __restrict__ cur_dst,
    int* __restrict__ list_src, int* __restrict__ list_src_e,
    int* __restrict__ list_dst, int* __restrict__ list_dst_e) {
  __shared__ __align__(16) __half xs[NT_ * 320];   // 40 KB, swizzled rows
  int bp = blockIdx.x;
  int t = threadIdx.x;

  if (bp >= NB_PROJ_) {                 // ---- fill role ----
    int i = (bp - NB_PROJ_) * 256 + t;
    if (i < PE_) {
      int p = i / E_;
      int s = esrc[i], d = edst[i];
      int ps = atomicAdd(&cur_src[p * N_ + s], 1);
      list_src[ps] = d;
      list_src_e[ps] = i;
      int pd = atomicAdd(&cur_dst[p * M_ + d], 1);
      list_dst[pd] = s;
      list_dst_e[pd] = i;
    }
    return;
  }

  int p = bp / TILES_, tile = bp % TILES_;
  int base = tile * NT_;
  int rows = min(NT_, N_ - base);

  // ---- stage x -> xs (swizzled) AND xh (dense) in one pass ----
  const float* xb = x + (size_t)(p * N_ + base) * 320;
  __half* xo = xh + (size_t)(p * N_ + base) * 320;
  for (int idx = t; idx < rows * 40; idx += 256) {
    int row = idx / 40, col = idx % 40;      // col: 8-half chunk
    const float4* s4 = (const float4*)&xb[row * 320 + col * 8];
    float4 v0 = s4[0], v1 = s4[1];
    union { __half2 h[4]; float4 f; } u4;
    u4.h[0] = __floats2half2_rn(v0.x, v0.y);
    u4.h[1] = __floats2half2_rn(v0.z, v0.w);
    u4.h[2] = __floats2half2_rn(v1.x, v1.y);
    u4.h[3] = __floats2half2_rn(v1.z, v1.w);
    *(float4*)&xs[row * 320 + ((col * 8) ^ ((row & 7) << 3))] = u4.f;
    if (write_xh) *(float4*)&xo[row * 320 + col * 8] = u4.f;
  }
  __syncthreads();

  int w = t >> 6, l = t & 63;
  int l15 = l & 15, l4 = l >> 4;
  int nA = w * 16 + l15;                    // A-fragment row (node in tile)
  int swzA = (nA & 7) << 3;

  // ---- y via MFMA: per c, [16x32] per wave ----
  #pragma unroll
  for (int c = 0; c < C_; ++c) {
    f16x8 a0 = ld8(&xs[nA * 320 + ((c * 64 + 0  + l4 * 8) ^ swzA)]);
    f16x8 a1 = ld8(&xs[nA * 320 + ((c * 64 + 32 + l4 * 8) ^ swzA)]);
    #pragma unroll
    for (int ct = 0; ct < 2; ++ct) {
      const __half* wb = &wn1h[(size_t)(c * 32 + ct * 16 + l15) * PFP_ + p * 64];
      f16x8 b0 = ld8(&wb[0  + l4 * 8]);
      f16x8 b1 = ld8(&wb[32 + l4 * 8]);
      f32x4 acc = (f32x4){0.f, 0.f, 0.f, 0.f};
      acc = __builtin_amdgcn_mfma_f32_16x16x32_f16(a0, b0, acc, 0, 0, 0);
      acc = __builtin_amdgcn_mfma_f32_16x16x32_f16(a1, b1, acc, 0, 0, 0);
      #pragma unroll
      for (int r = 0; r < 4; ++r) {
        int node = w * 16 + l4 * 4 + r;
        if (node < rows)
          y[(size_t)(p * N_ + base + node) * CFN_ + c * 32 + ct * 16 + l15] =
              __float2half(acc[r]);
      }
    }
  }

  // ---- xdot: 320 work items over 256 threads (swizzled reads) ----
  for (int idx = t; idx < C_ * NT_; idx += 256) {
    int cx = idx >> 6, nodex = idx & 63;
    if (nodex < rows) {
      int swz = (nodex & 7) << 3;
      const float2* wer = (const float2*)&We[(p * C_ + cx) * FPFN_];
      float s = 0.f;
      #pragma unroll
      for (int i = 0; i < 32; ++i) {
        __half2 xv = *(const __half2*)&xs[nodex * 320 + ((cx * 64 + 2 * i) ^ swz)];
        float2 wv = wer[i];
        s += __low2float(xv) * wv.x + __high2float(xv) * wv.y;
      }
      xdot[(size_t)(p * N_ + base + nodex) * C_ + cx] = s;
    }
  }
}

// ====================== nexus: gather y; MLP; + fused edge-weight softmax ======
__global__ __launch_bounds__(320) void k_nexus(
    const __half* __restrict__ y,
    const int* __restrict__ off_dst, const int* __restrict__ list_dst,
    const int* __restrict__ list_dst_e, const int* __restrict__ esrc,
    const float* __restrict__ bn1,
    const float* __restrict__ Wn2, const float* __restrict__ bn2,
    const float* __restrict__ We,
    const float* __restrict__ xdot, const float* __restrict__ be,
    __half* __restrict__ nout, __half* __restrict__ wbuf) {
  __shared__ float part[4][CFN_];
  __shared__ __align__(16) float h1S[CFN_];
  __shared__ __align__(16) float h2S[CFN_];
  __shared__ float ndS[P_ * C_];
  __shared__ float beS[P_ * C_];
  int m = blockIdx.x;
  int t = threadIdx.x;               // 320 = 4 groups x 80 half2-lanes
  int g = t / 80, u2 = t % 80;

  float afx = 0.f, afy = 0.f;
  #pragma unroll
  for (int p = 0; p < P_; ++p) {
    int o0 = off_dst[p * M_ + m];
    int o1 = off_dst[p * M_ + m + 1];
    const __half2* yp2 = (const __half2*)(y + (size_t)p * N_ * CFN_);
    for (int e0 = o0 + g; e0 < o1; e0 += 8) {   // batch-2 per group
      int e1 = e0 + 4;
      int s0 = list_dst[e0];
      int s1 = list_dst[e1 < o1 ? e1 : e0];
      __half2 v0 = yp2[(size_t)s0 * 80 + u2];
      __half2 v1 = yp2[(size_t)s1 * 80 + u2];
      afx += __low2float(v0); afy += __high2float(v0);
      if (e1 < o1) { afx += __low2float(v1); afy += __high2float(v1); }
    }
  }
  part[g][2 * u2]     = afx;
  part[g][2 * u2 + 1] = afy;
  __syncthreads();
  if (t < CFN_) {
    float pre = part[0][t] + part[1][t] + part[2][t] + part[3][t] + bn1[t];
    h1S[t] = fast_tanh(pre);
  }
  __syncthreads();
  if (t < CFN_) {
    int c = t >> 5;
    const float4* f4 = (const float4*)&h1S[c * FN_];
    const float4* w4 = (const float4*)&Wn2[(size_t)t * FN_];
    float a = bn2[t];
    #pragma unroll
    for (int i = 0; i < FN_ / 4; ++i) {
      float4 f = f4[i], wv = w4[i];
      a += f.x * wv.x + f.y * wv.y + f.z * wv.z + f.w * wv.w;
    }
    float nv = fast_tanh(a);
    h2S[t] = nv;
    nout[(size_t)m * CFN_ + t] = __float2half(nv);
  }
  __syncthreads();
  if (t < P_ * C_) {                 // ndot kept in LDS only
    int p = t / C_, cc = t % C_;
    const float* wv = &We[(p * C_ + cc) * FPFN_ + FP_];
    float a = 0.f;
    #pragma unroll
    for (int j = 0; j < FN_; ++j) a += h2S[cc * FN_ + j] * wv[j];
    ndS[t] = a;
    beS[t] = be[t];
  }
  __syncthreads();
  // ---- edge-weight phase: softmax once per edge, wbuf[i][c] fp16 ----
  #pragma unroll
  for (int p = 0; p < P_; ++p) {
    int o0 = off_dst[p * M_ + m];
    int o1 = off_dst[p * M_ + m + 1];
    for (int e = o0 + t; e < o1; e += 320) {
      int i = list_dst_e[e];
      int src = esrc[i];
      const float* xd = &xdot[(size_t)(p * N_ + src) * C_];
      float lg[C_];
      #pragma unroll
      for (int cc = 0; cc < C_; ++cc) lg[cc] = xd[cc] + ndS[p * C_ + cc] + beS[p * C_ + cc];
      float mx = fmaxf(fmaxf(fmaxf(lg[0], lg[1]), fmaxf(lg[2], lg[3])), lg[4]);
      float s = 0.f;
      #pragma unroll
      for (int cc = 0; cc < C_; ++cc) { lg[cc] = __expf(lg[cc] - mx); s += lg[cc]; }
      float inv = __fdividef(1.0f, s);
      __half* wp = &wbuf[(size_t)i * C_];
      #pragma unroll
      for (int cc = 0; cc < C_; ++cc) wp[cc] = __float2half(lg[cc] * inv);
    }
  }
}

// ====================== MFMA decoder: precomputed weights, unroll-2 gather =====
// Fragments: A row=l&15, k=8*(l>>4)+j; B col=l&15, k=8*(l>>4)+j;
//            D col=l&15, row=4*(l>>4)+reg.
template<int XH>
__global__ __launch_bounds__(128, 6) void k_dec(
    const float* __restrict__ x, const __half* __restrict__ xh,
    const __half* __restrict__ nout, const __half* __restrict__ wbuf,
    const int* __restrict__ off_src, const int* __restrict__ list_src,
    const int* __restrict__ list_src_e,
    const __half* __restrict__ w1h, const float* __restrict__ bd1,
    const __half* __restrict__ w2h, const float* __restrict__ bd2,
    float* __restrict__ out) {
  __shared__ __align__(16) __half featS[NTD_ * 104];   // 13.3 KB

  int bp = blockIdx.x;
  int pc = bp / TILESD_;
  int tile = bp % TILESD_;
  int p = pc / C_, c = pc % C_;
  int base = tile * NTD_;
  int rows = min(NTD_, N_ - base);

  int t = threadIdx.x;
  int w = t >> 6, l = t & 63;
  int l15 = l & 15, l4 = l >> 4;

  // ---- stage x ----
  if constexpr (XH) {
    for (int idx = t; idx < NTD_ * 8; idx += 128) {
      int node = idx >> 3, q = idx & 7;
      if (node < rows) {
        float4 v = *(const float4*)&xh[(size_t)(p * N_ + base + node) * 320 + c * 64 + q * 8];
        *(float4*)&featS[node * 104 + q * 8] = v;
      }
    }
  } else {
    for (int idx = t; idx < NTD_ * 16; idx += 128) {
      int node = idx >> 4, fq = idx & 15;
      if (node < rows) {
        float4 v = *(const float4*)&x[(size_t)(p * N_ + base + node) * 320 + c * 64 + fq * 4];
        __half2* dst = (__half2*)&featS[node * 104 + fq * 4];
        dst[0] = __floats2half2_rn(v.x, v.y);
        dst[1] = __floats2half2_rn(v.z, v.w);
      }
    }
  }
  // ---- fused aggregation: precomputed weights, 2 threads/node, unroll-2 edges -
  {
    int nd = t >> 1, hf = t & 1;
    if (nd < rows) {
      int pn = p * N_ + base + nd;
      int o0 = off_src[pn], o1 = off_src[pn + 1];
      float acc[16];
      #pragma unroll
      for (int i = 0; i < 16; ++i) acc[i] = 0.f;
      for (int e = o0; e < o1; e += 2) {
        int e1 = e + 1;
        bool has1 = (e1 < o1);
        int d0 = list_src[e];
        int i0 = list_src_e[e];
        int d1 = list_src[has1 ? e1 : e];
        int i1 = list_src_e[has1 ? e1 : e];
        float wg0 = __half2float(wbuf[(size_t)i0 * C_ + c]);
        float wg1 = __half2float(wbuf[(size_t)i1 * C_ + c]);
        const __half2* nr0 = (const __half2*)&nout[(size_t)d0 * CFN_ + c * FN_ + hf * 16];
        const __half2* nr1 = (const __half2*)&nout[(size_t)d1 * CFN_ + c * FN_ + hf * 16];
        __half2 v0[8], v1[8];
        #pragma unroll
        for (int i = 0; i < 8; ++i) v0[i] = nr0[i];
        #pragma unroll
        for (int i = 0; i < 8; ++i) v1[i] = nr1[i];
        #pragma unroll
        for (int i = 0; i < 8; ++i) {
          acc[2 * i]     += wg0 * __low2float(v0[i]);
          acc[2 * i + 1] += wg0 * __high2float(v0[i]);
        }
        if (has1) {
          #pragma unroll
          for (int i = 0; i < 8; ++i) {
            acc[2 * i]     += wg1 * __low2float(v1[i]);
            acc[2 * i + 1] += wg1 * __high2float(v1[i]);
          }
        }
      }
      float invd = __fdividef(1.0f, fmaxf((float)(o1 - o0), 1.0f));
      __half2* dst2 = (__half2*)&featS[nd * 104 + 64 + hf * 16];
      #pragma unroll
      for (int i = 0; i < 8; ++i)
        dst2[i] = __floats2half2_rn(acc[2 * i] * invd, acc[2 * i + 1] * invd);
    }
  }
  __syncthreads();

  int rbase = w * 32;   // this wave's node window [rbase, rbase+32)
  const __half* w1g = w1h + (size_t)(p * C_ + c) * 64 * 96;
  const __half* w2g = w2h + (size_t)(p * C_ + c) * 64 * 64;

  // ---- L1: acc[rt][tt] += A(feat) x B(W1) ----
  f32x4 acc[2][4];
  #pragma unroll
  for (int tt = 0; tt < 4; ++tt) {
    float bv = bd1[(p * C_ + c) * FP_ + tt * 16 + l15];
    #pragma unroll
    for (int rt = 0; rt < 2; ++rt) acc[rt][tt] = (f32x4){bv, bv, bv, bv};
  }
  #pragma unroll
  for (int s = 0; s < 3; ++s) {
    f16x8 a0 = ld8(&featS[(rbase + l15) * 104 + s * 32 + l4 * 8]);
    f16x8 a1 = ld8(&featS[(rbase + 16 + l15) * 104 + s * 32 + l4 * 8]);
    #pragma unroll
    for (int tt = 0; tt < 4; ++tt) {
      f16x8 b = ld8(&w1g[(tt * 16 + l15) * 96 + s * 32 + l4 * 8]);
      acc[0][tt] = __builtin_amdgcn_mfma_f32_16x16x32_f16(a0, b, acc[0][tt], 0, 0, 0);
      acc[1][tt] = __builtin_amdgcn_mfma_f32_16x16x32_f16(a1, b, acc[1][tt], 0, 0, 0);
    }
  }
  // tanh -> h overlaid into featS cols 0..63 (same-wave rows only)
  #pragma unroll
  for (int rt = 0; rt < 2; ++rt)
    #pragma unroll
    for (int tt = 0; tt < 4; ++tt) {
      #pragma unroll
      for (int r = 0; r < 4; ++r) {
        int nrow = rbase + rt * 16 + l4 * 4 + r;
        featS[nrow * 104 + tt * 16 + l15] = __float2half(fast_tanh(acc[rt][tt][r]));
      }
    }

  // ---- L2: acc2 += A(h in featS) x B(W2) ----
  f32x4 acc2[2][4];
  #pragma unroll
  for (int tt = 0; tt < 4; ++tt) {
    float bv = bd2[(p * C_ + c) * FP_ + tt * 16 + l15];
    #pragma unroll
    for (int rt = 0; rt < 2; ++rt) acc2[rt][tt] = (f32x4){bv, bv, bv, bv};
  }
  #pragma unroll
  for (int s = 0; s < 2; ++s) {
    f16x8 a0 = ld8(&featS[(rbase + l15) * 104 + s * 32 + l4 * 8]);
    f16x8 a1 = ld8(&featS[(rbase + 16 + l15) * 104 + s * 32 + l4 * 8]);
    #pragma unroll
    for (int tt = 0; tt < 4; ++tt) {
      f16x8 b = ld8(&w2g[(tt * 16 + l15) * 64 + s * 32 + l4 * 8]);
      acc2[0][tt] = __builtin_amdgcn_mfma_f32_16x16x32_f16(a0, b, acc2[0][tt], 0, 0, 0);
      acc2[1][tt] = __builtin_amdgcn_mfma_f32_16x16x32_f16(a1, b, acc2[1][tt], 0, 0, 0);
    }
  }
  // tanh -> global
  #pragma unroll
  for (int rt = 0; rt < 2; ++rt)
    #pragma unroll
    for (int tt = 0; tt < 4; ++tt) {
      #pragma unroll
      for (int r = 0; r < 4; ++r) {
        int nrow = rbase + rt * 16 + l4 * 4 + r;
        int node = base + nrow;
        if (node < N_) {
          out[(size_t)(p * N_ + node) * 320 + c * 64 + tt * 16 + l15] =
              fast_tanh(acc2[rt][tt][r]);
        }
      }
    }
}

// ====================== launch ======================
// workspace layout (4-byte words):
#define WS_Y      0ll          // half[48,000,000] = 24,000,000 words
#define WS_NOUT   24000000ll   // half[4,800,000] = 2,400,000 words
#define WS_LISTSE 26400000ll   // int[600,000]
#define WS_WBUF   27000000ll   // half[3,000,000] = 1,500,000 words
#define WS_XDOT   28800000ll   // float[1,500,000]
#define WS_OFFS   30750000ll   // int[300,001]
#define WS_OFFD   31050001ll   // int[90,001]
#define WS_CURS   31140002ll   // int[300,000]
#define WS_CURD   31440002ll   // int[90,000]  (contiguous with CURS)
#define WS_LISTS  31530002ll   // int[600,000]
#define WS_LISTD  32130002ll   // int[600,000]
#define WS_AUX1   32730002ll   // int[512]
#define WS_AUX2   32730514ll   // int[512]
#define WS_W1H    32731026ll   // half[92,160] = 46,080 words
#define WS_W2H    32777106ll   // half[61,440] = 30,720 words
#define WS_LISTDE 32808000ll   // int[600,000]
#define WS_WN1H   33408000ll   // half[30,720] = 15,360 words
#define WS_XH     33423360ll   // half[96,000,000] = 48,000,000 words (optional)
#define WS_XH_END_BYTES ((WS_XH + 48000000ll) * 4ll)   // 325,693,440

extern "C" void kernel_launch(void* const* d_in, const int* in_sizes, int n_in,
                              void* d_out, int out_size, void* d_ws, size_t ws_size,
                              hipStream_t stream) {
  const float* x   = (const float*)d_in[0];
  const int* esrc  = (const int*)d_in[2];
  const int* edst  = (const int*)d_in[3];
  const float* Wn1 = (const float*)d_in[4];
  const float* bn1 = (const float*)d_in[5];
  const float* Wn2 = (const float*)d_in[6];
  const float* bn2 = (const float*)d_in[7];
  const float* We  = (const float*)d_in[8];
  const float* be  = (const float*)d_in[9];
  const float* Wd1 = (const float*)d_in[10];
  const float* bd1 = (const float*)d_in[11];
  const float* Wd2 = (const float*)d_in[12];
  const float* bd2 = (const float*)d_in[13];
  float* out = (float*)d_out;

  float* wsf = (float*)d_ws;
  int*   wsi = (int*)d_ws;
  __half* ybuf = (__half*)d_ws;
  __half* nout = (__half*)(wsi + WS_NOUT);
  __half* wbuf = (__half*)(wsi + WS_WBUF);
  float* xdot = wsf + WS_XDOT;
  int* off_src = wsi + WS_OFFS;
  int* off_dst = wsi + WS_OFFD;
  int* cur_src = wsi + WS_CURS;
  int* cur_dst = wsi + WS_CURD;
  int* list_src = wsi + WS_LISTS;
  int* list_src_e = wsi + WS_LISTSE;
  int* list_dst = wsi + WS_LISTD;
  int* list_dst_e = wsi + WS_LISTDE;
  int* aux1 = wsi + WS_AUX1;
  int* aux2 = wsi + WS_AUX2;
  __half* w1h = (__half*)(wsi + WS_W1H);
  __half* w2h = (__half*)(wsi + WS_W2H);
  __half* wn1h = (__half*)(wsi + WS_WN1H);
  __half* xh  = (__half*)(wsi + WS_XH);

  int use_xh = (ws_size >= (size_t)WS_XH_END_BYTES) ? 1 : 0;

  // ---- CSR build (consolidated; weight conversions ride along with count) ----
  hipMemsetAsync(cur_src, 0, (PN_ + PM_) * sizeof(int), stream);
  k_countw<<<NB_CNT_ + NB_WC_, 256, 0, stream>>>(esrc, edst, cur_src, cur_dst,
                                                 Wd1, Wd2, Wn1, w1h, w2h, wn1h);
  k_scan1c<<<NB_S_ + NB_D_, 256, 0, stream>>>(cur_src, off_src, aux1,
                                              cur_dst, off_dst, aux2);
  k_scan2c<<<2, 1024, 0, stream>>>(aux1, off_src + PN_, aux2, off_dst + PM_);
  k_scan3c<<<(PN_ + PM_ + 255) / 256, 256, 0, stream>>>(off_src, aux1, cur_src,
                                                        off_dst, aux2, cur_dst);

  // ---- projx (MFMA) + fill (fused, independent work) ----
  k_projfill<<<NB_PROJ_ + NB_FILL_, 256, 0, stream>>>(
      x, wn1h, We, ybuf, xdot, xh, use_xh,
      esrc, edst, cur_src, cur_dst,
      list_src, list_src_e, list_dst, list_dst_e);

  // ---- nexus (+ edge-weight softmax) ----
  k_nexus<<<M_, 320, 0, stream>>>(ybuf, off_dst, list_dst, list_dst_e, esrc,
                                  bn1, Wn2, bn2, We, xdot, be, nout, wbuf);

  // ---- decoder ----
  if (use_xh) {
    k_dec<1><<<P_ * C_ * TILESD_, 128, 0, stream>>>(x, xh, nout, wbuf,
                                                    off_src, list_src, list_src_e,
                                                    w1h, bd1, w2h, bd2, out);
  } else {
    k_dec<0><<<P_ * C_ * TILESD_, 128, 0, stream>>>(x, xh, nout, wbuf,
                                                    off_src, list_src, list_src_e,
                                                    w1h, bd1, w2h, bd2, out);
  }
}

// Round 18
// 783.235 us; speedup vs baseline: 1.1082x; 1.0156x over previous
//
#include <hip/hip_runtime.h>
#include <hip/hip_fp16.h>

#define P_ 3
#define N_ 100000
#define M_ 30000
#define E_ 200000
#define C_ 5
#define FP_ 64
#define FN_ 32
#define PFP_ 192     // P*FP
#define FPFN_ 96     // FP+FN
#define PE_ 600000   // P*E
#define PN_ 300000   // P*N
#define PM_ 90000    // P*M
#define NT_ 64       // nodes per projx tile
#define TILES_ ((N_ + NT_ - 1) / NT_)     // 1563
#define NTD_ 128     // nodes per decoder tile
#define TILESD_ ((N_ + NTD_ - 1) / NTD_)  // 782
#define CFN_ 160     // C*FN
#define NW1_ 92160   // 15*64*96
#define NW2_ 61440   // 15*64*64
#define NWN1_ 30720  // 160*192
#define NB_S_ ((PN_ + 1023) / 1024)       // 293
#define NB_D_ ((PM_ + 1023) / 1024)       // 88
#define NB_CNT_ ((PE_ + 255) / 256)       // 2344 count blocks
#define NB_WC_ ((NW1_ + 255) / 256)       // 360 wconv blocks
#define NB_PROJ_ (P_ * TILES_)            // 4689
#define NB_FILL_ ((PE_ + 255) / 256)      // 2344

typedef _Float16 f16x8 __attribute__((ext_vector_type(8)));
typedef float f32x4 __attribute__((ext_vector_type(4)));

__device__ __forceinline__ float fast_tanh(float v) {
  // 1 - 2/(e^{2v}+1): inf-safe both directions, no clamp needed
  float t = __expf(2.0f * v);
  return 1.0f - __fdividef(2.0f, t + 1.0f);
}

__device__ __forceinline__ f16x8 ld8(const __half* p) {
  return *(const f16x8*)(const void*)p;
}

// ====================== count + weight conversions (fused) ======================
__global__ void k_countw(const int* __restrict__ esrc, const int* __restrict__ edst,
                         int* __restrict__ cnt_src, int* __restrict__ cnt_dst,
                         const float* __restrict__ Wd1, const float* __restrict__ Wd2,
                         const float* __restrict__ Wn1,
                         __half* __restrict__ w1h, __half* __restrict__ w2h,
                         __half* __restrict__ wn1h) {
  int b = blockIdx.x;
  if (b < NB_CNT_) {
    int i = b * 256 + threadIdx.x;
    if (i >= PE_) return;
    int p = i / E_;
    atomicAdd(&cnt_src[p * N_ + esrc[i]], 1);
    atomicAdd(&cnt_dst[p * M_ + edst[i]], 1);
  } else {
    int i = (b - NB_CNT_) * 256 + threadIdx.x;
    if (i < NW1_) w1h[i] = __float2half(Wd1[i]);
    if (i < NW2_) w2h[i] = __float2half(Wd2[i]);
    if (i < NWN1_) wn1h[i] = __float2half(Wn1[i]);
  }
}

__global__ void k_scan1c(const int* __restrict__ in_s, int* __restrict__ out_s,
                         int* __restrict__ aux_s,
                         const int* __restrict__ in_d, int* __restrict__ out_d,
                         int* __restrict__ aux_d) {
  __shared__ int lds[256];
  int b = blockIdx.x, t = threadIdx.x;
  const int* in;
  int* out;
  int* aux;
  int n;
  if (b < NB_S_) { in = in_s; out = out_s; aux = aux_s; n = PN_; }
  else           { b -= NB_S_; in = in_d; out = out_d; aux = aux_d; n = PM_; }
  int base = b * 1024 + t * 4;
  int v0 = (base + 0 < n) ? in[base + 0] : 0;
  int v1 = (base + 1 < n) ? in[base + 1] : 0;
  int v2 = (base + 2 < n) ? in[base + 2] : 0;
  int v3 = (base + 3 < n) ? in[base + 3] : 0;
  lds[t] = v0 + v1 + v2 + v3;
  __syncthreads();
  for (int off = 1; off < 256; off <<= 1) {
    int xv = (t >= off) ? lds[t - off] : 0;
    __syncthreads();
    lds[t] += xv;
    __syncthreads();
  }
  if (t == 255) aux[b] = lds[255];
  int run = (t == 0) ? 0 : lds[t - 1];
  if (base + 0 < n) out[base + 0] = run; run += v0;
  if (base + 1 < n) out[base + 1] = run; run += v1;
  if (base + 2 < n) out[base + 2] = run; run += v2;
  if (base + 3 < n) out[base + 3] = run;
}

__global__ void k_scan2c(int* __restrict__ aux_s, int* __restrict__ end_s,
                         int* __restrict__ aux_d, int* __restrict__ end_d) {
  __shared__ int lds[1024];
  int t = threadIdx.x;
  int* aux = (blockIdx.x == 0) ? aux_s : aux_d;
  int* offe = (blockIdx.x == 0) ? end_s : end_d;
  int nb = (blockIdx.x == 0) ? NB_S_ : NB_D_;
  lds[t] = (t < nb) ? aux[t] : 0;
  __syncthreads();
  for (int off = 1; off < 1024; off <<= 1) {
    int xv = (t >= off) ? lds[t - off] : 0;
    __syncthreads();
    lds[t] += xv;
    __syncthreads();
  }
  if (t < nb) aux[t] = (t == 0) ? 0 : lds[t - 1];
  if (t == 0) offe[0] = lds[nb - 1];
}

__global__ void k_scan3c(int* __restrict__ off_s, const int* __restrict__ aux_s,
                         int* __restrict__ cur_s,
                         int* __restrict__ off_d, const int* __restrict__ aux_d,
                         int* __restrict__ cur_d) {
  int i = blockIdx.x * 256 + threadIdx.x;
  if (i < PN_) {
    int v = off_s[i] + aux_s[i >> 10];
    off_s[i] = v;
    cur_s[i] = v;
  } else if (i < PN_ + PM_) {
    int j = i - PN_;
    int v = off_d[j] + aux_d[j >> 10];
    off_d[j] = v;
    cur_d[j] = v;
  }
}

// ====================== projx: MFMA y-projection (+ xdot, + xh) + fill =========
// xs rows XOR-swizzled: element h of row r lives at half-offset h ^ ((r&7)<<3).
// Fragments: A row=l&15, k=8*(l>>4)+j; B col=l&15, k=8*(l>>4)+j;
//            D col=l&15, row=4*(l>>4)+reg.
__global__ __launch_bounds__(256) void k_projfill(
    const float* __restrict__ x, const __half* __restrict__ wn1h,
    const float* __restrict__ We,
    __half* __restrict__ y, float* __restrict__ xdot,
    __half* __restrict__ xh, int write_xh,
    const int* __restrict__ esrc, const int* __restrict__ edst,
    int* __restrict__ cur_src, int* __restrict__ cur_dst,
    int* __restrict__ list_src, int* __restrict__ list_src_e,
    int* __restrict__ list_dst, int* __restrict__ list_dst_e) {
  __shared__ __align__(16) __half xs[NT_ * 320];   // 40 KB, swizzled rows
  int bp = blockIdx.x;
  int t = threadIdx.x;

  if (bp >= NB_PROJ_) {                 // ---- fill role ----
    int i = (bp - NB_PROJ_) * 256 + t;
    if (i < PE_) {
      int p = i / E_;
      int s = esrc[i], d = edst[i];
      int ps = atomicAdd(&cur_src[p * N_ + s], 1);
      list_src[ps] = d;
      list_src_e[ps] = i;
      int pd = atomicAdd(&cur_dst[p * M_ + d], 1);
      list_dst[pd] = s;
      list_dst_e[pd] = i;
    }
    return;
  }

  int p = bp / TILES_, tile = bp % TILES_;
  int base = tile * NT_;
  int rows = min(NT_, N_ - base);

  // ---- stage x -> xs (swizzled) AND xh (dense) in one pass ----
  const float* xb = x + (size_t)(p * N_ + base) * 320;
  __half* xo = xh + (size_t)(p * N_ + base) * 320;
  for (int idx = t; idx < rows * 40; idx += 256) {
    int row = idx / 40, col = idx % 40;      // col: 8-half chunk
    const float4* s4 = (const float4*)&xb[row * 320 + col * 8];
    float4 v0 = s4[0], v1 = s4[1];
    union { __half2 h[4]; float4 f; } u4;
    u4.h[0] = __floats2half2_rn(v0.x, v0.y);
    u4.h[1] = __floats2half2_rn(v0.z, v0.w);
    u4.h[2] = __floats2half2_rn(v1.x, v1.y);
    u4.h[3] = __floats2half2_rn(v1.z, v1.w);
    *(float4*)&xs[row * 320 + ((col * 8) ^ ((row & 7) << 3))] = u4.f;
    if (write_xh) *(float4*)&xo[row * 320 + col * 8] = u4.f;
  }
  __syncthreads();

  int w = t >> 6, l = t & 63;
  int l15 = l & 15, l4 = l >> 4;
  int nA = w * 16 + l15;                    // A-fragment row (node in tile)
  int swzA = (nA & 7) << 3;

  // ---- y via MFMA: per c, [16x32] per wave ----
  #pragma unroll
  for (int c = 0; c < C_; ++c) {
    f16x8 a0 = ld8(&xs[nA * 320 + ((c * 64 + 0  + l4 * 8) ^ swzA)]);
    f16x8 a1 = ld8(&xs[nA * 320 + ((c * 64 + 32 + l4 * 8) ^ swzA)]);
    #pragma unroll
    for (int ct = 0; ct < 2; ++ct) {
      const __half* wb = &wn1h[(size_t)(c * 32 + ct * 16 + l15) * PFP_ + p * 64];
      f16x8 b0 = ld8(&wb[0  + l4 * 8]);
      f16x8 b1 = ld8(&wb[32 + l4 * 8]);
      f32x4 acc = (f32x4){0.f, 0.f, 0.f, 0.f};
      acc = __builtin_amdgcn_mfma_f32_16x16x32_f16(a0, b0, acc, 0, 0, 0);
      acc = __builtin_amdgcn_mfma_f32_16x16x32_f16(a1, b1, acc, 0, 0, 0);
      #pragma unroll
      for (int r = 0; r < 4; ++r) {
        int node = w * 16 + l4 * 4 + r;
        if (node < rows)
          y[(size_t)(p * N_ + base + node) * CFN_ + c * 32 + ct * 16 + l15] =
              __float2half(acc[r]);
      }
    }
  }

  // ---- xdot: swizzled reads ----
  for (int idx = t; idx < C_ * NT_; idx += 256) {
    int cx = idx >> 6, nodex = idx & 63;
    if (nodex < rows) {
      int swz = (nodex & 7) << 3;
      const float2* wer = (const float2*)&We[(p * C_ + cx) * FPFN_];
      float s = 0.f;
      #pragma unroll
      for (int i = 0; i < 32; ++i) {
        __half2 xv = *(const __half2*)&xs[nodex * 320 + ((cx * 64 + 2 * i) ^ swz)];
        float2 wv = wer[i];
        s += __low2float(xv) * wv.x + __high2float(xv) * wv.y;
      }
      xdot[(size_t)(p * N_ + base + nodex) * C_ + cx] = s;
    }
  }
}

// ====================== nexus: gather y; MLP; + fused edge-weight softmax ======
__global__ __launch_bounds__(320) void k_nexus(
    const __half* __restrict__ y,
    const int* __restrict__ off_dst, const int* __restrict__ list_dst,
    const int* __restrict__ list_dst_e, const int* __restrict__ esrc,
    const float* __restrict__ bn1,
    const float* __restrict__ Wn2, const float* __restrict__ bn2,
    const float* __restrict__ We,
    const float* __restrict__ xdot, const float* __restrict__ be,
    __half* __restrict__ nout, __half* __restrict__ wbuf) {
  __shared__ float part[4][CFN_];
  __shared__ __align__(16) float h1S[CFN_];
  __shared__ __align__(16) float h2S[CFN_];
  __shared__ float ndS[P_ * C_];
  __shared__ float beS[P_ * C_];
  int m = blockIdx.x;
  int t = threadIdx.x;               // 320 = 4 groups x 80 half2-lanes
  int g = t / 80, u2 = t % 80;

  float afx = 0.f, afy = 0.f;
  #pragma unroll
  for (int p = 0; p < P_; ++p) {
    int o0 = off_dst[p * M_ + m];
    int o1 = off_dst[p * M_ + m + 1];
    const __half2* yp2 = (const __half2*)(y + (size_t)p * N_ * CFN_);
    for (int e0 = o0 + g; e0 < o1; e0 += 8) {   // batch-2 per group
      int e1 = e0 + 4;
      int s0 = list_dst[e0];
      int s1 = list_dst[e1 < o1 ? e1 : e0];
      __half2 v0 = yp2[(size_t)s0 * 80 + u2];
      __half2 v1 = yp2[(size_t)s1 * 80 + u2];
      afx += __low2float(v0); afy += __high2float(v0);
      if (e1 < o1) { afx += __low2float(v1); afy += __high2float(v1); }
    }
  }
  part[g][2 * u2]     = afx;
  part[g][2 * u2 + 1] = afy;
  __syncthreads();
  if (t < CFN_) {
    float pre = part[0][t] + part[1][t] + part[2][t] + part[3][t] + bn1[t];
    h1S[t] = fast_tanh(pre);
  }
  __syncthreads();
  if (t < CFN_) {
    int c = t >> 5;
    const float4* f4 = (const float4*)&h1S[c * FN_];
    const float4* w4 = (const float4*)&Wn2[(size_t)t * FN_];
    float a = bn2[t];
    #pragma unroll
    for (int i = 0; i < FN_ / 4; ++i) {
      float4 f = f4[i], wv = w4[i];
      a += f.x * wv.x + f.y * wv.y + f.z * wv.z + f.w * wv.w;
    }
    float nv = fast_tanh(a);
    h2S[t] = nv;
    nout[(size_t)m * CFN_ + t] = __float2half(nv);
  }
  __syncthreads();
  if (t < P_ * C_) {                 // ndot kept in LDS only
    int p = t / C_, cc = t % C_;
    const float* wv = &We[(p * C_ + cc) * FPFN_ + FP_];
    float a = 0.f;
    #pragma unroll
    for (int j = 0; j < FN_; ++j) a += h2S[cc * FN_ + j] * wv[j];
    ndS[t] = a;
    beS[t] = be[t];
  }
  __syncthreads();
  // ---- edge-weight phase: softmax once per edge, wbuf[i][c] fp16 ----
  #pragma unroll
  for (int p = 0; p < P_; ++p) {
    int o0 = off_dst[p * M_ + m];
    int o1 = off_dst[p * M_ + m + 1];
    for (int e = o0 + t; e < o1; e += 320) {
      int i = list_dst_e[e];
      int src = esrc[i];
      const float* xd = &xdot[(size_t)(p * N_ + src) * C_];
      float lg[C_];
      #pragma unroll
      for (int cc = 0; cc < C_; ++cc) lg[cc] = xd[cc] + ndS[p * C_ + cc] + beS[p * C_ + cc];
      float mx = fmaxf(fmaxf(fmaxf(lg[0], lg[1]), fmaxf(lg[2], lg[3])), lg[4]);
      float s = 0.f;
      #pragma unroll
      for (int cc = 0; cc < C_; ++cc) { lg[cc] = __expf(lg[cc] - mx); s += lg[cc]; }
      float inv = __fdividef(1.0f, s);
      __half* wp = &wbuf[(size_t)i * C_];
      #pragma unroll
      for (int cc = 0; cc < C_; ++cc) wp[cc] = __float2half(lg[cc] * inv);
    }
  }
}

// ====================== MFMA decoder: 128-node tiles, 4 waves, hfma2 aggr ======
// Fragments: A row=l&15, k=8*(l>>4)+j; B col=l&15, k=8*(l>>4)+j;
//            D col=l&15, row=4*(l>>4)+reg.
template<int XH>
__global__ __launch_bounds__(256, 6) void k_dec(
    const float* __restrict__ x, const __half* __restrict__ xh,
    const __half* __restrict__ nout, const __half* __restrict__ wbuf,
    const int* __restrict__ off_src, const int* __restrict__ list_src,
    const int* __restrict__ list_src_e,
    const __half* __restrict__ w1h, const float* __restrict__ bd1,
    const __half* __restrict__ w2h, const float* __restrict__ bd2,
    float* __restrict__ out) {
  __shared__ __align__(16) __half featS[NTD_ * 104];   // 26.6 KB

  int bp = blockIdx.x;
  int pc = bp / TILESD_;
  int tile = bp % TILESD_;
  int p = pc / C_, c = pc % C_;
  int base = tile * NTD_;
  int rows = min(NTD_, N_ - base);

  int t = threadIdx.x;
  int w = t >> 6, l = t & 63;
  int l15 = l & 15, l4 = l >> 4;

  // ---- stage x ----
  if constexpr (XH) {
    for (int idx = t; idx < NTD_ * 8; idx += 256) {
      int node = idx >> 3, q = idx & 7;
      if (node < rows) {
        float4 v = *(const float4*)&xh[(size_t)(p * N_ + base + node) * 320 + c * 64 + q * 8];
        *(float4*)&featS[node * 104 + q * 8] = v;
      }
    }
  } else {
    for (int idx = t; idx < NTD_ * 16; idx += 256) {
      int node = idx >> 4, fq = idx & 15;
      if (node < rows) {
        float4 v = *(const float4*)&x[(size_t)(p * N_ + base + node) * 320 + c * 64 + fq * 4];
        __half2* dst = (__half2*)&featS[node * 104 + fq * 4];
        dst[0] = __floats2half2_rn(v.x, v.y);
        dst[1] = __floats2half2_rn(v.z, v.w);
      }
    }
  }
  // ---- fused aggregation: fp16 packed accum, 2 threads/node, unroll-2 edges ---
  {
    int nd = t >> 1, hf = t & 1;
    if (nd < rows) {
      int pn = p * N_ + base + nd;
      int o0 = off_src[pn], o1 = off_src[pn + 1];
      __half2 acc[8];
      #pragma unroll
      for (int i = 0; i < 8; ++i) acc[i] = __floats2half2_rn(0.f, 0.f);
      for (int e = o0; e < o1; e += 2) {
        int e1 = e + 1;
        bool has1 = (e1 < o1);
        int d0 = list_src[e];
        int i0 = list_src_e[e];
        int d1 = list_src[has1 ? e1 : e];
        int i1 = list_src_e[has1 ? e1 : e];
        __half wg0h = wbuf[(size_t)i0 * C_ + c];
        __half wg1h = wbuf[(size_t)i1 * C_ + c];
        const __half2* nr0 = (const __half2*)&nout[(size_t)d0 * CFN_ + c * FN_ + hf * 16];
        const __half2* nr1 = (const __half2*)&nout[(size_t)d1 * CFN_ + c * FN_ + hf * 16];
        __half2 v0[8], v1[8];
        #pragma unroll
        for (int i = 0; i < 8; ++i) v0[i] = nr0[i];
        #pragma unroll
        for (int i = 0; i < 8; ++i) v1[i] = nr1[i];
        __half2 wg0 = __half2half2(wg0h);
        #pragma unroll
        for (int i = 0; i < 8; ++i) acc[i] = __hfma2(wg0, v0[i], acc[i]);
        if (has1) {
          __half2 wg1 = __half2half2(wg1h);
          #pragma unroll
          for (int i = 0; i < 8; ++i) acc[i] = __hfma2(wg1, v1[i], acc[i]);
        }
      }
      float invd = __fdividef(1.0f, fmaxf((float)(o1 - o0), 1.0f));
      __half2 invd2 = __float2half2_rn(invd);
      __half2* dst2 = (__half2*)&featS[nd * 104 + 64 + hf * 16];
      #pragma unroll
      for (int i = 0; i < 8; ++i) dst2[i] = __hmul2(acc[i], invd2);
    }
  }
  __syncthreads();

  int rbase = w * 32;   // this wave's node window [rbase, rbase+32)
  const __half* w1g = w1h + (size_t)(p * C_ + c) * 64 * 96;
  const __half* w2g = w2h + (size_t)(p * C_ + c) * 64 * 64;

  // ---- L1: acc[rt][tt] += A(feat) x B(W1) ----
  f32x4 acc[2][4];
  #pragma unroll
  for (int tt = 0; tt < 4; ++tt) {
    float bv = bd1[(p * C_ + c) * FP_ + tt * 16 + l15];
    #pragma unroll
    for (int rt = 0; rt < 2; ++rt) acc[rt][tt] = (f32x4){bv, bv, bv, bv};
  }
  #pragma unroll
  for (int s = 0; s < 3; ++s) {
    f16x8 a0 = ld8(&featS[(rbase + l15) * 104 + s * 32 + l4 * 8]);
    f16x8 a1 = ld8(&featS[(rbase + 16 + l15) * 104 + s * 32 + l4 * 8]);
    #pragma unroll
    for (int tt = 0; tt < 4; ++tt) {
      f16x8 b = ld8(&w1g[(tt * 16 + l15) * 96 + s * 32 + l4 * 8]);
      acc[0][tt] = __builtin_amdgcn_mfma_f32_16x16x32_f16(a0, b, acc[0][tt], 0, 0, 0);
      acc[1][tt] = __builtin_amdgcn_mfma_f32_16x16x32_f16(a1, b, acc[1][tt], 0, 0, 0);
    }
  }
  // tanh -> h overlaid into featS cols 0..63 (same-wave rows only)
  #pragma unroll
  for (int rt = 0; rt < 2; ++rt)
    #pragma unroll
    for (int tt = 0; tt < 4; ++tt) {
      #pragma unroll
      for (int r = 0; r < 4; ++r) {
        int nrow = rbase + rt * 16 + l4 * 4 + r;
        featS[nrow * 104 + tt * 16 + l15] = __float2half(fast_tanh(acc[rt][tt][r]));
      }
    }

  // ---- L2: acc2 += A(h in featS) x B(W2) ----
  f32x4 acc2[2][4];
  #pragma unroll
  for (int tt = 0; tt < 4; ++tt) {
    float bv = bd2[(p * C_ + c) * FP_ + tt * 16 + l15];
    #pragma unroll
    for (int rt = 0; rt < 2; ++rt) acc2[rt][tt] = (f32x4){bv, bv, bv, bv};
  }
  #pragma unroll
  for (int s = 0; s < 2; ++s) {
    f16x8 a0 = ld8(&featS[(rbase + l15) * 104 + s * 32 + l4 * 8]);
    f16x8 a1 = ld8(&featS[(rbase + 16 + l15) * 104 + s * 32 + l4 * 8]);
    #pragma unroll
    for (int tt = 0; tt < 4; ++tt) {
      f16x8 b = ld8(&w2g[(tt * 16 + l15) * 64 + s * 32 + l4 * 8]);
      acc2[0][tt] = __builtin_amdgcn_mfma_f32_16x16x32_f16(a0, b, acc2[0][tt], 0, 0, 0);
      acc2[1][tt] = __builtin_amdgcn_mfma_f32_16x16x32_f16(a1, b, acc2[1][tt], 0, 0, 0);
    }
  }
  // tanh -> global
  #pragma unroll
  for (int rt = 0; rt < 2; ++rt)
    #pragma unroll
    for (int tt = 0; tt < 4; ++tt) {
      #pragma unroll
      for (int r = 0; r < 4; ++r) {
        int nrow = rbase + rt * 16 + l4 * 4 + r;
        int node = base + nrow;
        if (node < N_) {
          out[(size_t)(p * N_ + node) * 320 + c * 64 + tt * 16 + l15] =
              fast_tanh(acc2[rt][tt][r]);
        }
      }
    }
}

// ====================== launch ======================
// workspace layout (4-byte words):
#define WS_Y      0ll          // half[48,000,000] = 24,000,000 words
#define WS_NOUT   24000000ll   // half[4,800,000] = 2,400,000 words
#define WS_LISTSE 26400000ll   // int[600,000]
#define WS_WBUF   27000000ll   // half[3,000,000] = 1,500,000 words
#define WS_XDOT   28800000ll   // float[1,500,000]
#define WS_OFFS   30750000ll   // int[300,001]
#define WS_OFFD   31050001ll   // int[90,001]
#define WS_CURS   31140002ll   // int[300,000]
#define WS_CURD   31440002ll   // int[90,000]  (contiguous with CURS)
#define WS_LISTS  31530002ll   // int[600,000]
#define WS_LISTD  32130002ll   // int[600,000]
#define WS_AUX1   32730002ll   // int[512]
#define WS_AUX2   32730514ll   // int[512]
#define WS_W1H    32731026ll   // half[92,160] = 46,080 words
#define WS_W2H    32777106ll   // half[61,440] = 30,720 words
#define WS_LISTDE 32808000ll   // int[600,000]
#define WS_WN1H   33408000ll   // half[30,720] = 15,360 words
#define WS_XH     33423360ll   // half[96,000,000] = 48,000,000 words (optional)
#define WS_XH_END_BYTES ((WS_XH + 48000000ll) * 4ll)   // 325,693,440

extern "C" void kernel_launch(void* const* d_in, const int* in_sizes, int n_in,
                              void* d_out, int out_size, void* d_ws, size_t ws_size,
                              hipStream_t stream) {
  const float* x   = (const float*)d_in[0];
  const int* esrc  = (const int*)d_in[2];
  const int* edst  = (const int*)d_in[3];
  const float* Wn1 = (const float*)d_in[4];
  const float* bn1 = (const float*)d_in[5];
  const float* Wn2 = (const float*)d_in[6];
  const float* bn2 = (const float*)d_in[7];
  const float* We  = (const float*)d_in[8];
  const float* be  = (const float*)d_in[9];
  const float* Wd1 = (const float*)d_in[10];
  const float* bd1 = (const float*)d_in[11];
  const float* Wd2 = (const float*)d_in[12];
  const float* bd2 = (const float*)d_in[13];
  float* out = (float*)d_out;

  float* wsf = (float*)d_ws;
  int*   wsi = (int*)d_ws;
  __half* ybuf = (__half*)d_ws;
  __half* nout = (__half*)(wsi + WS_NOUT);
  __half* wbuf = (__half*)(wsi + WS_WBUF);
  float* xdot = wsf + WS_XDOT;
  int* off_src = wsi + WS_OFFS;
  int* off_dst = wsi + WS_OFFD;
  int* cur_src = wsi + WS_CURS;
  int* cur_dst = wsi + WS_CURD;
  int* list_src = wsi + WS_LISTS;
  int* list_src_e = wsi + WS_LISTSE;
  int* list_dst = wsi + WS_LISTD;
  int* list_dst_e = wsi + WS_LISTDE;
  int* aux1 = wsi + WS_AUX1;
  int* aux2 = wsi + WS_AUX2;
  __half* w1h = (__half*)(wsi + WS_W1H);
  __half* w2h = (__half*)(wsi + WS_W2H);
  __half* wn1h = (__half*)(wsi + WS_WN1H);
  __half* xh  = (__half*)(wsi + WS_XH);

  int use_xh = (ws_size >= (size_t)WS_XH_END_BYTES) ? 1 : 0;

  // ---- CSR build (consolidated; weight conversions ride along with count) ----
  hipMemsetAsync(cur_src, 0, (PN_ + PM_) * sizeof(int), stream);
  k_countw<<<NB_CNT_ + NB_WC_, 256, 0, stream>>>(esrc, edst, cur_src, cur_dst,
                                                 Wd1, Wd2, Wn1, w1h, w2h, wn1h);
  k_scan1c<<<NB_S_ + NB_D_, 256, 0, stream>>>(cur_src, off_src, aux1,
                                              cur_dst, off_dst, aux2);
  k_scan2c<<<2, 1024, 0, stream>>>(aux1, off_src + PN_, aux2, off_dst + PM_);
  k_scan3c<<<(PN_ + PM_ + 255) / 256, 256, 0, stream>>>(off_src, aux1, cur_src,
                                                        off_dst, aux2, cur_dst);

  // ---- projx (MFMA) + fill (fused, independent work) ----
  k_projfill<<<NB_PROJ_ + NB_FILL_, 256, 0, stream>>>(
      x, wn1h, We, ybuf, xdot, xh, use_xh,
      esrc, edst, cur_src, cur_dst,
      list_src, list_src_e, list_dst, list_dst_e);

  // ---- nexus (+ edge-weight softmax) ----
  k_nexus<<<M_, 320, 0, stream>>>(ybuf, off_dst, list_dst, list_dst_e, esrc,
                                  bn1, Wn2, bn2, We, xdot, be, nout, wbuf);

  // ---- decoder ----
  if (use_xh) {
    k_dec<1><<<P_ * C_ * TILESD_, 256, 0, stream>>>(x, xh, nout, wbuf,
                                                    off_src, list_src, list_src_e,
                                                    w1h, bd1, w2h, bd2, out);
  } else {
    k_dec<0><<<P_ * C_ * TILESD_, 256, 0, stream>>>(x, xh, nout, wbuf,
                                                    off_src, list_src, list_src_e,
                                                    w1h, bd1, w2h, bd2, out);
  }
}

// Round 19
// 718.459 us; speedup vs baseline: 1.2082x; 1.0902x over previous
//
#include <hip/hip_runtime.h>
#include <hip/hip_fp16.h>

#define P_ 3
#define N_ 100000
#define M_ 30000
#define E_ 200000
#define C_ 5
#define FP_ 64
#define FN_ 32
#define PFP_ 192     // P*FP
#define FPFN_ 96     // FP+FN
#define PE_ 600000   // P*E
#define PN_ 300000   // P*N
#define PM_ 90000    // P*M
#define NT_ 64       // nodes per projx tile
#define TILES_ ((N_ + NT_ - 1) / NT_)     // 1563
#define NTD_ 128     // nodes per decoder tile
#define TILESD_ ((N_ + NTD_ - 1) / NTD_)  // 782
#define CFN_ 160     // C*FN
#define NW1_ 92160   // 15*64*96
#define NW2_ 61440   // 15*64*64
#define NWN1_ 30720  // 160*192
#define NB_S_ ((PN_ + 1023) / 1024)       // 293
#define NB_D_ ((PM_ + 1023) / 1024)       // 88
#define NB_CNT_ ((PE_ + 255) / 256)       // 2344 count blocks
#define NB_WC_ ((NW1_ + 255) / 256)       // 360 wconv blocks
#define NB_PROJ_ (P_ * TILES_)            // 4689
#define NB_FILL_ ((PE_ + 511) / 512)      // 1172

typedef _Float16 f16x8 __attribute__((ext_vector_type(8)));
typedef float f32x4 __attribute__((ext_vector_type(4)));

__device__ __forceinline__ float fast_tanh(float v) {
  // 1 - 2/(e^{2v}+1): inf-safe both directions, no clamp needed
  float t = __expf(2.0f * v);
  return 1.0f - __fdividef(2.0f, t + 1.0f);
}

__device__ __forceinline__ f16x8 ld8(const __half* p) {
  return *(const f16x8*)(const void*)p;
}

// ====================== count + weight conversions (fused) ======================
__global__ void k_countw(const int* __restrict__ esrc, const int* __restrict__ edst,
                         int* __restrict__ cnt_src, int* __restrict__ cnt_dst,
                         const float* __restrict__ Wd1, const float* __restrict__ Wd2,
                         const float* __restrict__ Wn1,
                         __half* __restrict__ w1h, __half* __restrict__ w2h,
                         __half* __restrict__ wn1h) {
  int b = blockIdx.x;
  if (b < NB_CNT_) {
    int i = b * 256 + threadIdx.x;
    if (i >= PE_) return;
    int p = i / E_;
    atomicAdd(&cnt_src[p * N_ + esrc[i]], 1);
    atomicAdd(&cnt_dst[p * M_ + edst[i]], 1);
  } else {
    int i = (b - NB_CNT_) * 256 + threadIdx.x;
    if (i < NW1_) w1h[i] = __float2half(Wd1[i]);
    if (i < NW2_) w2h[i] = __float2half(Wd2[i]);
    if (i < NWN1_) wn1h[i] = __float2half(Wn1[i]);
  }
}

__global__ void k_scan1c(const int* __restrict__ in_s, int* __restrict__ out_s,
                         int* __restrict__ aux_s,
                         const int* __restrict__ in_d, int* __restrict__ out_d,
                         int* __restrict__ aux_d) {
  __shared__ int lds[256];
  int b = blockIdx.x, t = threadIdx.x;
  const int* in;
  int* out;
  int* aux;
  int n;
  if (b < NB_S_) { in = in_s; out = out_s; aux = aux_s; n = PN_; }
  else           { b -= NB_S_; in = in_d; out = out_d; aux = aux_d; n = PM_; }
  int base = b * 1024 + t * 4;
  int v0 = (base + 0 < n) ? in[base + 0] : 0;
  int v1 = (base + 1 < n) ? in[base + 1] : 0;
  int v2 = (base + 2 < n) ? in[base + 2] : 0;
  int v3 = (base + 3 < n) ? in[base + 3] : 0;
  lds[t] = v0 + v1 + v2 + v3;
  __syncthreads();
  for (int off = 1; off < 256; off <<= 1) {
    int xv = (t >= off) ? lds[t - off] : 0;
    __syncthreads();
    lds[t] += xv;
    __syncthreads();
  }
  if (t == 255) aux[b] = lds[255];
  int run = (t == 0) ? 0 : lds[t - 1];
  if (base + 0 < n) out[base + 0] = run; run += v0;
  if (base + 1 < n) out[base + 1] = run; run += v1;
  if (base + 2 < n) out[base + 2] = run; run += v2;
  if (base + 3 < n) out[base + 3] = run;
}

__global__ void k_scan2c(int* __restrict__ aux_s, int* __restrict__ end_s,
                         int* __restrict__ aux_d, int* __restrict__ end_d) {
  __shared__ int lds[1024];
  int t = threadIdx.x;
  int* aux = (blockIdx.x == 0) ? aux_s : aux_d;
  int* offe = (blockIdx.x == 0) ? end_s : end_d;
  int nb = (blockIdx.x == 0) ? NB_S_ : NB_D_;
  lds[t] = (t < nb) ? aux[t] : 0;
  __syncthreads();
  for (int off = 1; off < 1024; off <<= 1) {
    int xv = (t >= off) ? lds[t - off] : 0;
    __syncthreads();
    lds[t] += xv;
    __syncthreads();
  }
  if (t < nb) aux[t] = (t == 0) ? 0 : lds[t - 1];
  if (t == 0) offe[0] = lds[nb - 1];
}

__global__ void k_scan3c(int* __restrict__ off_s, const int* __restrict__ aux_s,
                         int* __restrict__ cur_s,
                         int* __restrict__ off_d, const int* __restrict__ aux_d,
                         int* __restrict__ cur_d) {
  int i = blockIdx.x * 256 + threadIdx.x;
  if (i < PN_) {
    int v = off_s[i] + aux_s[i >> 10];
    off_s[i] = v;
    cur_s[i] = v;
  } else if (i < PN_ + PM_) {
    int j = i - PN_;
    int v = off_d[j] + aux_d[j >> 10];
    off_d[j] = v;
    cur_d[j] = v;
  }
}

// ====================== projx: MFMA y-projection (+ xdot, + xh) + fill =========
// 512 threads = 8 waves: wave w -> node-quarter (w&3), ct-half (w>>2).
// xs rows XOR-swizzled: element h of row r lives at half-offset h ^ ((r&7)<<3).
// Fragments: A row=l&15, k=8*(l>>4)+j; B col=l&15, k=8*(l>>4)+j;
//            D col=l&15, row=4*(l>>4)+reg.
__global__ __launch_bounds__(512) void k_projfill(
    const float* __restrict__ x, const __half* __restrict__ wn1h,
    const float* __restrict__ We,
    __half* __restrict__ y, float* __restrict__ xdot,
    __half* __restrict__ xh, int write_xh,
    const int* __restrict__ esrc, const int* __restrict__ edst,
    int* __restrict__ cur_src, int* __restrict__ cur_dst,
    int* __restrict__ list_src, int* __restrict__ list_src_e,
    int* __restrict__ list_dst, int* __restrict__ list_dst_e) {
  __shared__ __align__(16) __half xs[NT_ * 320];   // 40 KB, swizzled rows
  int bp = blockIdx.x;
  int t = threadIdx.x;

  if (bp >= NB_PROJ_) {                 // ---- fill role ----
    int i = (bp - NB_PROJ_) * 512 + t;
    if (i < PE_) {
      int p = i / E_;
      int s = esrc[i], d = edst[i];
      int ps = atomicAdd(&cur_src[p * N_ + s], 1);
      list_src[ps] = d;
      list_src_e[ps] = i;
      int pd = atomicAdd(&cur_dst[p * M_ + d], 1);
      list_dst[pd] = s;
      list_dst_e[pd] = i;
    }
    return;
  }

  int p = bp / TILES_, tile = bp % TILES_;
  int base = tile * NT_;
  int rows = min(NT_, N_ - base);

  // ---- stage x -> xs (swizzled) AND xh (dense) in one pass ----
  const float* xb = x + (size_t)(p * N_ + base) * 320;
  __half* xo = xh + (size_t)(p * N_ + base) * 320;
  for (int idx = t; idx < rows * 40; idx += 512) {
    int row = idx / 40, col = idx % 40;      // col: 8-half chunk
    const float4* s4 = (const float4*)&xb[row * 320 + col * 8];
    float4 v0 = s4[0], v1 = s4[1];
    union { __half2 h[4]; float4 f; } u4;
    u4.h[0] = __floats2half2_rn(v0.x, v0.y);
    u4.h[1] = __floats2half2_rn(v0.z, v0.w);
    u4.h[2] = __floats2half2_rn(v1.x, v1.y);
    u4.h[3] = __floats2half2_rn(v1.z, v1.w);
    *(float4*)&xs[row * 320 + ((col * 8) ^ ((row & 7) << 3))] = u4.f;
    if (write_xh) *(float4*)&xo[row * 320 + col * 8] = u4.f;
  }
  __syncthreads();

  int w = t >> 6, l = t & 63;
  int l15 = l & 15, l4 = l >> 4;
  int q4 = w & 3, ct = w >> 2;
  int nA = q4 * 16 + l15;                   // A-fragment row (node in tile)
  int swzA = (nA & 7) << 3;

  // ---- y via MFMA: per c, [16x16] per wave ----
  #pragma unroll
  for (int c = 0; c < C_; ++c) {
    f16x8 a0 = ld8(&xs[nA * 320 + ((c * 64 + 0  + l4 * 8) ^ swzA)]);
    f16x8 a1 = ld8(&xs[nA * 320 + ((c * 64 + 32 + l4 * 8) ^ swzA)]);
    const __half* wb = &wn1h[(size_t)(c * 32 + ct * 16 + l15) * PFP_ + p * 64];
    f16x8 b0 = ld8(&wb[0  + l4 * 8]);
    f16x8 b1 = ld8(&wb[32 + l4 * 8]);
    f32x4 acc = (f32x4){0.f, 0.f, 0.f, 0.f};
    acc = __builtin_amdgcn_mfma_f32_16x16x32_f16(a0, b0, acc, 0, 0, 0);
    acc = __builtin_amdgcn_mfma_f32_16x16x32_f16(a1, b1, acc, 0, 0, 0);
    #pragma unroll
    for (int r = 0; r < 4; ++r) {
      int node = q4 * 16 + l4 * 4 + r;
      if (node < rows)
        y[(size_t)(p * N_ + base + node) * CFN_ + c * 32 + ct * 16 + l15] =
            __float2half(acc[r]);
    }
  }

  // ---- xdot: swizzled reads (320 items over 512 threads) ----
  for (int idx = t; idx < C_ * NT_; idx += 512) {
    int cx = idx >> 6, nodex = idx & 63;
    if (nodex < rows) {
      int swz = (nodex & 7) << 3;
      const float2* wer = (const float2*)&We[(p * C_ + cx) * FPFN_];
      float s = 0.f;
      #pragma unroll
      for (int i = 0; i < 32; ++i) {
        __half2 xv = *(const __half2*)&xs[nodex * 320 + ((cx * 64 + 2 * i) ^ swz)];
        float2 wv = wer[i];
        s += __low2float(xv) * wv.x + __high2float(xv) * wv.y;
      }
      xdot[(size_t)(p * N_ + base + nodex) * C_ + cx] = s;
    }
  }
}

// ====================== nexus: gather y; MLP; + fused edge-weight softmax ======
// y-gather: 16 edge-groups x 20 float4-lanes (16B loads, deeper edge parallelism)
__global__ __launch_bounds__(320) void k_nexus(
    const __half* __restrict__ y,
    const int* __restrict__ off_dst, const int* __restrict__ list_dst,
    const int* __restrict__ list_dst_e, const int* __restrict__ esrc,
    const float* __restrict__ bn1,
    const float* __restrict__ Wn2, const float* __restrict__ bn2,
    const float* __restrict__ We,
    const float* __restrict__ xdot, const float* __restrict__ be,
    __half* __restrict__ nout, __half* __restrict__ wbuf) {
  __shared__ float part[16][CFN_];    // 10.24 KB
  __shared__ __align__(16) float h1S[CFN_];
  __shared__ __align__(16) float h2S[CFN_];
  __shared__ float ndS[P_ * C_];
  __shared__ float beS[P_ * C_];
  int m = blockIdx.x;
  int t = threadIdx.x;               // 320 = 16 groups x 20 float4-lanes
  int g = t / 20, u4 = t % 20;

  float acc[8];
  #pragma unroll
  for (int i = 0; i < 8; ++i) acc[i] = 0.f;
  #pragma unroll
  for (int p = 0; p < P_; ++p) {
    int o0 = off_dst[p * M_ + m];
    int o1 = off_dst[p * M_ + m + 1];
    const __half* yp = y + (size_t)p * N_ * CFN_;
    for (int e = o0 + g; e < o1; e += 16) {
      int s0 = list_dst[e];
      float4 v = *(const float4*)&yp[(size_t)s0 * CFN_ + u4 * 8];
      union { float4 f; __half2 h[4]; } uu;
      uu.f = v;
      #pragma unroll
      for (int i = 0; i < 4; ++i) {
        acc[2 * i]     += __low2float(uu.h[i]);
        acc[2 * i + 1] += __high2float(uu.h[i]);
      }
    }
  }
  #pragma unroll
  for (int i = 0; i < 8; ++i) part[g][u4 * 8 + i] = acc[i];
  __syncthreads();
  if (t < CFN_) {
    float pre = bn1[t];
    #pragma unroll
    for (int gg = 0; gg < 16; ++gg) pre += part[gg][t];
    h1S[t] = fast_tanh(pre);
  }
  __syncthreads();
  if (t < CFN_) {
    int c = t >> 5;
    const float4* f4 = (const float4*)&h1S[c * FN_];
    const float4* w4 = (const float4*)&Wn2[(size_t)t * FN_];
    float a = bn2[t];
    #pragma unroll
    for (int i = 0; i < FN_ / 4; ++i) {
      float4 f = f4[i], wv = w4[i];
      a += f.x * wv.x + f.y * wv.y + f.z * wv.z + f.w * wv.w;
    }
    float nv = fast_tanh(a);
    h2S[t] = nv;
    nout[(size_t)m * CFN_ + t] = __float2half(nv);
  }
  __syncthreads();
  if (t < P_ * C_) {                 // ndot kept in LDS only
    int p = t / C_, cc = t % C_;
    const float* wv = &We[(p * C_ + cc) * FPFN_ + FP_];
    float a = 0.f;
    #pragma unroll
    for (int j = 0; j < FN_; ++j) a += h2S[cc * FN_ + j] * wv[j];
    ndS[t] = a;
    beS[t] = be[t];
  }
  __syncthreads();
  // ---- edge-weight phase: softmax once per edge, wbuf[i][c] fp16 ----
  #pragma unroll
  for (int p = 0; p < P_; ++p) {
    int o0 = off_dst[p * M_ + m];
    int o1 = off_dst[p * M_ + m + 1];
    for (int e = o0 + t; e < o1; e += 320) {
      int i = list_dst_e[e];
      int src = esrc[i];
      const float* xd = &xdot[(size_t)(p * N_ + src) * C_];
      float lg[C_];
      #pragma unroll
      for (int cc = 0; cc < C_; ++cc) lg[cc] = xd[cc] + ndS[p * C_ + cc] + beS[p * C_ + cc];
      float mx = fmaxf(fmaxf(fmaxf(lg[0], lg[1]), fmaxf(lg[2], lg[3])), lg[4]);
      float s = 0.f;
      #pragma unroll
      for (int cc = 0; cc < C_; ++cc) { lg[cc] = __expf(lg[cc] - mx); s += lg[cc]; }
      float inv = __fdividef(1.0f, s);
      __half* wp = &wbuf[(size_t)i * C_];
      #pragma unroll
      for (int cc = 0; cc < C_; ++cc) wp[cc] = __float2half(lg[cc] * inv);
    }
  }
}

// ====================== MFMA decoder: 128-node tiles, 4 waves, hfma2 aggr ======
// Fragments: A row=l&15, k=8*(l>>4)+j; B col=l&15, k=8*(l>>4)+j;
//            D col=l&15, row=4*(l>>4)+reg.
template<int XH>
__global__ __launch_bounds__(256, 6) void k_dec(
    const float* __restrict__ x, const __half* __restrict__ xh,
    const __half* __restrict__ nout, const __half* __restrict__ wbuf,
    const int* __restrict__ off_src, const int* __restrict__ list_src,
    const int* __restrict__ list_src_e,
    const __half* __restrict__ w1h, const float* __restrict__ bd1,
    const __half* __restrict__ w2h, const float* __restrict__ bd2,
    float* __restrict__ out) {
  __shared__ __align__(16) __half featS[NTD_ * 104];   // 26.6 KB

  int bp = blockIdx.x;
  int pc = bp / TILESD_;
  int tile = bp % TILESD_;
  int p = pc / C_, c = pc % C_;
  int base = tile * NTD_;
  int rows = min(NTD_, N_ - base);

  int t = threadIdx.x;
  int w = t >> 6, l = t & 63;
  int l15 = l & 15, l4 = l >> 4;

  // ---- stage x ----
  if constexpr (XH) {
    for (int idx = t; idx < NTD_ * 8; idx += 256) {
      int node = idx >> 3, q = idx & 7;
      if (node < rows) {
        float4 v = *(const float4*)&xh[(size_t)(p * N_ + base + node) * 320 + c * 64 + q * 8];
        *(float4*)&featS[node * 104 + q * 8] = v;
      }
    }
  } else {
    for (int idx = t; idx < NTD_ * 16; idx += 256) {
      int node = idx >> 4, fq = idx & 15;
      if (node < rows) {
        float4 v = *(const float4*)&x[(size_t)(p * N_ + base + node) * 320 + c * 64 + fq * 4];
        __half2* dst = (__half2*)&featS[node * 104 + fq * 4];
        dst[0] = __floats2half2_rn(v.x, v.y);
        dst[1] = __floats2half2_rn(v.z, v.w);
      }
    }
  }
  // ---- fused aggregation: fp16 packed accum, 2 threads/node, unroll-2 edges ---
  {
    int nd = t >> 1, hf = t & 1;
    if (nd < rows) {
      int pn = p * N_ + base + nd;
      int o0 = off_src[pn], o1 = off_src[pn + 1];
      __half2 acc[8];
      #pragma unroll
      for (int i = 0; i < 8; ++i) acc[i] = __floats2half2_rn(0.f, 0.f);
      for (int e = o0; e < o1; e += 2) {
        int e1 = e + 1;
        bool has1 = (e1 < o1);
        int d0 = list_src[e];
        int i0 = list_src_e[e];
        int d1 = list_src[has1 ? e1 : e];
        int i1 = list_src_e[has1 ? e1 : e];
        __half wg0h = wbuf[(size_t)i0 * C_ + c];
        __half wg1h = wbuf[(size_t)i1 * C_ + c];
        const __half2* nr0 = (const __half2*)&nout[(size_t)d0 * CFN_ + c * FN_ + hf * 16];
        const __half2* nr1 = (const __half2*)&nout[(size_t)d1 * CFN_ + c * FN_ + hf * 16];
        __half2 v0[8], v1[8];
        #pragma unroll
        for (int i = 0; i < 8; ++i) v0[i] = nr0[i];
        #pragma unroll
        for (int i = 0; i < 8; ++i) v1[i] = nr1[i];
        __half2 wg0 = __half2half2(wg0h);
        #pragma unroll
        for (int i = 0; i < 8; ++i) acc[i] = __hfma2(wg0, v0[i], acc[i]);
        if (has1) {
          __half2 wg1 = __half2half2(wg1h);
          #pragma unroll
          for (int i = 0; i < 8; ++i) acc[i] = __hfma2(wg1, v1[i], acc[i]);
        }
      }
      float invd = __fdividef(1.0f, fmaxf((float)(o1 - o0), 1.0f));
      __half2 invd2 = __float2half2_rn(invd);
      __half2* dst2 = (__half2*)&featS[nd * 104 + 64 + hf * 16];
      #pragma unroll
      for (int i = 0; i < 8; ++i) dst2[i] = __hmul2(acc[i], invd2);
    }
  }
  __syncthreads();

  int rbase = w * 32;   // this wave's node window [rbase, rbase+32)
  const __half* w1g = w1h + (size_t)(p * C_ + c) * 64 * 96;
  const __half* w2g = w2h + (size_t)(p * C_ + c) * 64 * 64;

  // ---- L1: acc[rt][tt] += A(feat) x B(W1) ----
  f32x4 acc[2][4];
  #pragma unroll
  for (int tt = 0; tt < 4; ++tt) {
    float bv = bd1[(p * C_ + c) * FP_ + tt * 16 + l15];
    #pragma unroll
    for (int rt = 0; rt < 2; ++rt) acc[rt][tt] = (f32x4){bv, bv, bv, bv};
  }
  #pragma unroll
  for (int s = 0; s < 3; ++s) {
    f16x8 a0 = ld8(&featS[(rbase + l15) * 104 + s * 32 + l4 * 8]);
    f16x8 a1 = ld8(&featS[(rbase + 16 + l15) * 104 + s * 32 + l4 * 8]);
    #pragma unroll
    for (int tt = 0; tt < 4; ++tt) {
      f16x8 b = ld8(&w1g[(tt * 16 + l15) * 96 + s * 32 + l4 * 8]);
      acc[0][tt] = __builtin_amdgcn_mfma_f32_16x16x32_f16(a0, b, acc[0][tt], 0, 0, 0);
      acc[1][tt] = __builtin_amdgcn_mfma_f32_16x16x32_f16(a1, b, acc[1][tt], 0, 0, 0);
    }
  }
  // tanh -> h overlaid into featS cols 0..63 (same-wave rows only)
  #pragma unroll
  for (int rt = 0; rt < 2; ++rt)
    #pragma unroll
    for (int tt = 0; tt < 4; ++tt) {
      #pragma unroll
      for (int r = 0; r < 4; ++r) {
        int nrow = rbase + rt * 16 + l4 * 4 + r;
        featS[nrow * 104 + tt * 16 + l15] = __float2half(fast_tanh(acc[rt][tt][r]));
      }
    }

  // ---- L2: acc2 += A(h in featS) x B(W2) ----
  f32x4 acc2[2][4];
  #pragma unroll
  for (int tt = 0; tt < 4; ++tt) {
    float bv = bd2[(p * C_ + c) * FP_ + tt * 16 + l15];
    #pragma unroll
    for (int rt = 0; rt < 2; ++rt) acc2[rt][tt] = (f32x4){bv, bv, bv, bv};
  }
  #pragma unroll
  for (int s = 0; s < 2; ++s) {
    f16x8 a0 = ld8(&featS[(rbase + l15) * 104 + s * 32 + l4 * 8]);
    f16x8 a1 = ld8(&featS[(rbase + 16 + l15) * 104 + s * 32 + l4 * 8]);
    #pragma unroll
    for (int tt = 0; tt < 4; ++tt) {
      f16x8 b = ld8(&w2g[(tt * 16 + l15) * 64 + s * 32 + l4 * 8]);
      acc2[0][tt] = __builtin_amdgcn_mfma_f32_16x16x32_f16(a0, b, acc2[0][tt], 0, 0, 0);
      acc2[1][tt] = __builtin_amdgcn_mfma_f32_16x16x32_f16(a1, b, acc2[1][tt], 0, 0, 0);
    }
  }
  // tanh -> global
  #pragma unroll
  for (int rt = 0; rt < 2; ++rt)
    #pragma unroll
    for (int tt = 0; tt < 4; ++tt) {
      #pragma unroll
      for (int r = 0; r < 4; ++r) {
        int nrow = rbase + rt * 16 + l4 * 4 + r;
        int node = base + nrow;
        if (node < N_) {
          out[(size_t)(p * N_ + node) * 320 + c * 64 + tt * 16 + l15] =
              fast_tanh(acc2[rt][tt][r]);
        }
      }
    }
}

// ====================== launch ======================
// workspace layout (4-byte words):
#define WS_Y      0ll          // half[48,000,000] = 24,000,000 words
#define WS_NOUT   24000000ll   // half[4,800,000] = 2,400,000 words
#define WS_LISTSE 26400000ll   // int[600,000]
#define WS_WBUF   27000000ll   // half[3,000,000] = 1,500,000 words
#define WS_XDOT   28800000ll   // float[1,500,000]
#define WS_OFFS   30750000ll   // int[300,001]
#define WS_OFFD   31050001ll   // int[90,001]
#define WS_CURS   31140002ll   // int[300,000]
#define WS_CURD   31440002ll   // int[90,000]  (contiguous with CURS)
#define WS_LISTS  31530002ll   // int[600,000]
#define WS_LISTD  32130002ll   // int[600,000]
#define WS_AUX1   32730002ll   // int[512]
#define WS_AUX2   32730514ll   // int[512]
#define WS_W1H    32731026ll   // half[92,160] = 46,080 words
#define WS_W2H    32777106ll   // half[61,440] = 30,720 words
#define WS_LISTDE 32808000ll   // int[600,000]
#define WS_WN1H   33408000ll   // half[30,720] = 15,360 words
#define WS_XH     33423360ll   // half[96,000,000] = 48,000,000 words (optional)
#define WS_XH_END_BYTES ((WS_XH + 48000000ll) * 4ll)   // 325,693,440

extern "C" void kernel_launch(void* const* d_in, const int* in_sizes, int n_in,
                              void* d_out, int out_size, void* d_ws, size_t ws_size,
                              hipStream_t stream) {
  const float* x   = (const float*)d_in[0];
  const int* esrc  = (const int*)d_in[2];
  const int* edst  = (const int*)d_in[3];
  const float* Wn1 = (const float*)d_in[4];
  const float* bn1 = (const float*)d_in[5];
  const float* Wn2 = (const float*)d_in[6];
  const float* bn2 = (const float*)d_in[7];
  const float* We  = (const float*)d_in[8];
  const float* be  = (const float*)d_in[9];
  const float* Wd1 = (const float*)d_in[10];
  const float* bd1 = (const float*)d_in[11];
  const float* Wd2 = (const float*)d_in[12];
  const float* bd2 = (const float*)d_in[13];
  float* out = (float*)d_out;

  float* wsf = (float*)d_ws;
  int*   wsi = (int*)d_ws;
  __half* ybuf = (__half*)d_ws;
  __half* nout = (__half*)(wsi + WS_NOUT);
  __half* wbuf = (__half*)(wsi + WS_WBUF);
  float* xdot = wsf + WS_XDOT;
  int* off_src = wsi + WS_OFFS;
  int* off_dst = wsi + WS_OFFD;
  int* cur_src = wsi + WS_CURS;
  int* cur_dst = wsi + WS_CURD;
  int* list_src = wsi + WS_LISTS;
  int* list_src_e = wsi + WS_LISTSE;
  int* list_dst = wsi + WS_LISTD;
  int* list_dst_e = wsi + WS_LISTDE;
  int* aux1 = wsi + WS_AUX1;
  int* aux2 = wsi + WS_AUX2;
  __half* w1h = (__half*)(wsi + WS_W1H);
  __half* w2h = (__half*)(wsi + WS_W2H);
  __half* wn1h = (__half*)(wsi + WS_WN1H);
  __half* xh  = (__half*)(wsi + WS_XH);

  int use_xh = (ws_size >= (size_t)WS_XH_END_BYTES) ? 1 : 0;

  // ---- CSR build (consolidated; weight conversions ride along with count) ----
  hipMemsetAsync(cur_src, 0, (PN_ + PM_) * sizeof(int), stream);
  k_countw<<<NB_CNT_ + NB_WC_, 256, 0, stream>>>(esrc, edst, cur_src, cur_dst,
                                                 Wd1, Wd2, Wn1, w1h, w2h, wn1h);
  k_scan1c<<<NB_S_ + NB_D_, 256, 0, stream>>>(cur_src, off_src, aux1,
                                              cur_dst, off_dst, aux2);
  k_scan2c<<<2, 1024, 0, stream>>>(aux1, off_src + PN_, aux2, off_dst + PM_);
  k_scan3c<<<(PN_ + PM_ + 255) / 256, 256, 0, stream>>>(off_src, aux1, cur_src,
                                                        off_dst, aux2, cur_dst);

  // ---- projx (MFMA, 512 threads) + fill (fused, independent work) ----
  k_projfill<<<NB_PROJ_ + NB_FILL_, 512, 0, stream>>>(
      x, wn1h, We, ybuf, xdot, xh, use_xh,
      esrc, edst, cur_src, cur_dst,
      list_src, list_src_e, list_dst, list_dst_e);

  // ---- nexus (+ edge-weight softmax) ----
  k_nexus<<<M_, 320, 0, stream>>>(ybuf, off_dst, list_dst, list_dst_e, esrc,
                                  bn1, Wn2, bn2, We, xdot, be, nout, wbuf);

  // ---- decoder ----
  if (use_xh) {
    k_dec<1><<<P_ * C_ * TILESD_, 256, 0, stream>>>(x, xh, nout, wbuf,
                                                    off_src, list_src, list_src_e,
                                                    w1h, bd1, w2h, bd2, out);
  } else {
    k_dec<0><<<P_ * C_ * TILESD_, 256, 0, stream>>>(x, xh, nout, wbuf,
                                                    off_src, list_src, list_src_e,
                                                    w1h, bd1, w2h, bd2, out);
  }
}